// Round 2
// baseline (1664.452 us; speedup 1.0000x reference)
//
#include <hip/hip_runtime.h>
#include <hip/hip_bf16.h>
#include <stdint.h>

using bf16 = __hip_bfloat16;

#define SCALE 0.17677669529663687f   // 32^-0.5

__device__ __forceinline__ float bf2f(bf16 v) { return __bfloat162float(v); }

__device__ __forceinline__ unsigned short f2bf(float f) {
    unsigned int u = __float_as_uint(f);
    unsigned int r = u + 0x7fffu + ((u >> 16) & 1u);   // RNE; inputs never NaN/Inf
    return (unsigned short)(r >> 16);
}

// load 8 consecutive bf16 (16B-aligned) -> 8 floats
__device__ __forceinline__ void load8bf(const bf16* p, float* f) {
    uint4 u = *reinterpret_cast<const uint4*>(p);
    f[0] = __uint_as_float(u.x << 16); f[1] = __uint_as_float(u.x & 0xffff0000u);
    f[2] = __uint_as_float(u.y << 16); f[3] = __uint_as_float(u.y & 0xffff0000u);
    f[4] = __uint_as_float(u.z << 16); f[5] = __uint_as_float(u.z & 0xffff0000u);
    f[6] = __uint_as_float(u.w << 16); f[7] = __uint_as_float(u.w & 0xffff0000u);
}

// ---------------------------------------------------------------------------
// K1: q/k/v = xt @ [Wq;Wkv]^T.  A[m][kk] = x[b][kk][pos] (transposed read).
// M=65536, K=256, N=768 (cols 0-255 -> q, 256-511 -> k, 512-767 -> v)
// grid (1024, 12), block 256.  64x64 tile, BK=16, 4x4 per thread.
// x, Wq, Wkv are fp32; q/k/v stored bf16.
// ---------------------------------------------------------------------------
__global__ __launch_bounds__(256) void qkv_gemm(
    const float* __restrict__ x, const float* __restrict__ Wq,
    const float* __restrict__ Wkv,
    bf16* __restrict__ q, bf16* __restrict__ k, bf16* __restrict__ v)
{
    __shared__ float As[16][65];
    __shared__ float Bs[16][65];
    const int m0 = blockIdx.x * 64;
    const int j0 = blockIdx.y * 64;           // 0..767
    const int b = m0 >> 12;
    const int pos0 = m0 & 4095;
    const float* Wbase; int jb;
    if (j0 < 256) { Wbase = Wq;  jb = j0; }
    else          { Wbase = Wkv; jb = j0 - 256; }
    const int tid = threadIdx.x;
    const int a_mm = tid & 63, a_kb = tid >> 6;      // A loader
    const int b_jj = tid >> 2, b_kb = (tid & 3) * 4; // B loader
    const int tx = tid & 15, ty = tid >> 4;
    float acc[4][4] = {};

    for (int k0 = 0; k0 < 256; k0 += 16) {
        #pragma unroll
        for (int u = 0; u < 4; ++u) {
            int kk = a_kb + 4 * u;
            As[kk][a_mm] = x[((size_t)(b * 256 + k0 + kk)) * 4096 + pos0 + a_mm];
        }
        {
            const float4 w4 = *reinterpret_cast<const float4*>(
                Wbase + (size_t)(jb + b_jj) * 256 + k0 + b_kb);
            Bs[b_kb + 0][b_jj] = w4.x;
            Bs[b_kb + 1][b_jj] = w4.y;
            Bs[b_kb + 2][b_jj] = w4.z;
            Bs[b_kb + 3][b_jj] = w4.w;
        }
        __syncthreads();
        #pragma unroll
        for (int kk = 0; kk < 16; ++kk) {
            float av[4], bv[4];
            #pragma unroll
            for (int i = 0; i < 4; ++i) av[i] = As[kk][ty * 4 + i];
            #pragma unroll
            for (int j = 0; j < 4; ++j) bv[j] = Bs[kk][tx * 4 + j];
            #pragma unroll
            for (int i = 0; i < 4; ++i)
                #pragma unroll
                for (int j = 0; j < 4; ++j) acc[i][j] += av[i] * bv[j];
        }
        __syncthreads();
    }
    // store: row m = m0+ty*4+i (pos), col ch = j0+tx*4+j  (4 consecutive ch = 8B)
    bf16* dst; int cb;
    if (j0 < 256)      { dst = q; cb = j0; }
    else if (j0 < 512) { dst = k; cb = j0 - 256; }
    else               { dst = v; cb = j0 - 512; }
    #pragma unroll
    for (int i = 0; i < 4; ++i) {
        int pos = pos0 + ty * 4 + i;
        ushort4 w;
        w.x = f2bf(acc[i][0]); w.y = f2bf(acc[i][1]);
        w.z = f2bf(acc[i][2]); w.w = f2bf(acc[i][3]);
        *reinterpret_cast<ushort4*>(dst + ((size_t)(b * 4096 + pos)) * 256 + cb + tx * 4) = w;
    }
}

// ---------------------------------------------------------------------------
// K2: agent tokens = adaptive avg pool 64x64 -> 7x7 of q.  grid 784, block 256.
// ---------------------------------------------------------------------------
__global__ __launch_bounds__(256) void pool_agent(
    const bf16* __restrict__ q, float* __restrict__ agent)
{
    int bid = blockIdx.x;
    int b = bid / 49, a = bid % 49;
    int py = a / 7, px = a % 7;
    int ys = (py * 64) / 7, ye = ((py + 1) * 64 + 6) / 7;
    int xs = (px * 64) / 7, xe = ((px + 1) * 64 + 6) / 7;
    int ch = threadIdx.x;
    float s = 0.f;
    for (int y = ys; y < ye; ++y)
        for (int x = xs; x < xe; ++x)
            s += bf2f(q[((size_t)(b * 4096) + y * 64 + x) * 256 + ch]);
    agent[((size_t)(b * 49) + a) * 256 + ch] = s / (float)((ye - ys) * (xe - xs));
}

// ---------------------------------------------------------------------------
// K3a: pbias[h][a][pos] = bilerp(an_bias[h][a])(y,x) + ah[h][a][y] + aw[h][a][x]
// jax.image.resize bilinear = half-pixel coords; edge weight renorm == clamp.
// grid 392 (= 8*49), block 256.
// ---------------------------------------------------------------------------
__global__ __launch_bounds__(256) void make_pbias(
    const float* __restrict__ an, const float* __restrict__ ahb,
    const float* __restrict__ awb, float* __restrict__ pbias)
{
    int bid = blockIdx.x;               // h*49 + a
    __shared__ float bb[49], ay[64], ax[64];
    int tid = threadIdx.x;
    if (tid < 49) bb[tid] = an[(size_t)bid * 49 + tid];
    if (tid < 64) {
        ay[tid] = ahb[(size_t)bid * 64 + tid];
        ax[tid] = awb[(size_t)bid * 64 + tid];
    }
    __syncthreads();
    for (int it = 0; it < 16; ++it) {
        int pos = it * 256 + tid;
        int y = pos >> 6, x = pos & 63;
        float fy = (y + 0.5f) * (7.f / 64.f) - 0.5f; fy = fminf(fmaxf(fy, 0.f), 6.f);
        float fx = (x + 0.5f) * (7.f / 64.f) - 0.5f; fx = fminf(fmaxf(fx, 0.f), 6.f);
        int y0 = (int)fy, x0 = (int)fx;
        int y1 = min(y0 + 1, 6), x1 = min(x0 + 1, 6);
        float wy = fy - y0, wx = fx - x0;
        float val = (1.f - wy) * ((1.f - wx) * bb[y0 * 7 + x0] + wx * bb[y0 * 7 + x1])
                  + wy * ((1.f - wx) * bb[y1 * 7 + x0] + wx * bb[y1 * 7 + x1]);
        pbias[(size_t)bid * 4096 + pos] = val + ay[y] + ax[x];
    }
}

// ---------------------------------------------------------------------------
// K3b: abias[h][pos][a] = bilerp(na_bias[h][a])(y,x) + ha[h][y][a] + wa[h][x][a]
// grid 392, block 256.
// ---------------------------------------------------------------------------
__global__ __launch_bounds__(256) void make_abias(
    const float* __restrict__ na, const float* __restrict__ hab,
    const float* __restrict__ wab, float* __restrict__ abias)
{
    int bid = blockIdx.x;
    int h = bid / 49, a = bid % 49;
    __shared__ float bb[49], hy[64], wx_[64];
    int tid = threadIdx.x;
    if (tid < 49) bb[tid] = na[(size_t)bid * 49 + tid];
    if (tid < 64) {
        hy[tid]  = hab[((size_t)(h * 64) + tid) * 49 + a];
        wx_[tid] = wab[((size_t)(h * 64) + tid) * 49 + a];
    }
    __syncthreads();
    for (int it = 0; it < 16; ++it) {
        int pos = it * 256 + tid;
        int y = pos >> 6, x = pos & 63;
        float fy = (y + 0.5f) * (7.f / 64.f) - 0.5f; fy = fminf(fmaxf(fy, 0.f), 6.f);
        float fx = (x + 0.5f) * (7.f / 64.f) - 0.5f; fx = fminf(fmaxf(fx, 0.f), 6.f);
        int y0 = (int)fy, x0 = (int)fx;
        int y1 = min(y0 + 1, 6), x1 = min(x0 + 1, 6);
        float wy = fy - y0, wxv = fx - x0;
        float val = (1.f - wy) * ((1.f - wxv) * bb[y0 * 7 + x0] + wxv * bb[y0 * 7 + x1])
                  + wy * ((1.f - wxv) * bb[y1 * 7 + x0] + wxv * bb[y1 * 7 + x1]);
        abias[((size_t)(h * 4096) + pos) * 49 + a] = val + hy[y] + wx_[x];
    }
}

// ---------------------------------------------------------------------------
// K4: stage-1 attention.  One block per (b,h,a): softmax over n=4096, then P.V.
// grid 6272 (=16*8*49), block 256.
// ---------------------------------------------------------------------------
__global__ __launch_bounds__(256) void stage1(
    const float* __restrict__ agent, const bf16* __restrict__ k,
    const bf16* __restrict__ v, const float* __restrict__ pbias,
    float* __restrict__ agent_v)
{
    int bid = blockIdx.x;
    int b = bid / 392, r = bid % 392;
    int h = r / 49, a = r % 49;
    __shared__ float aq[32];
    __shared__ float p[4096];
    __shared__ float red[256];
    __shared__ float pv[256];
    int tid = threadIdx.x;
    if (tid < 32) aq[tid] = agent[((size_t)(b * 49) + a) * 256 + h * 32 + tid] * SCALE;
    __syncthreads();

    const float* pb = pbias + ((size_t)(h * 49) + a) * 4096;
    float lmax = -1e30f;
    for (int it = 0; it < 16; ++it) {
        int nn = it * 256 + tid;
        const bf16* kr = k + ((size_t)(b * 4096) + nn) * 256 + h * 32;
        float s = 0.f;
        #pragma unroll
        for (int u = 0; u < 4; ++u) {
            float f[8]; load8bf(kr + u * 8, f);
            #pragma unroll
            for (int d = 0; d < 8; ++d) s += aq[u * 8 + d] * f[d];
        }
        s += pb[nn];
        p[nn] = s;
        lmax = fmaxf(lmax, s);
    }
    red[tid] = lmax; __syncthreads();
    for (int st = 128; st > 0; st >>= 1) {
        if (tid < st) red[tid] = fmaxf(red[tid], red[tid + st]);
        __syncthreads();
    }
    float m = red[0]; __syncthreads();
    float lsum = 0.f;
    for (int it = 0; it < 16; ++it) {
        int nn = it * 256 + tid;
        float e = __expf(p[nn] - m);
        p[nn] = e; lsum += e;
    }
    red[tid] = lsum; __syncthreads();
    for (int st = 128; st > 0; st >>= 1) {
        if (tid < st) red[tid] += red[tid + st];
        __syncthreads();
    }
    float inv = 1.f / red[0];
    // P.V: 8 groups of 32 lanes, group g covers nn in [g*512, g*512+512)
    int d = tid & 31, g = tid >> 5;
    float acc = 0.f;
    for (int nn = g * 512; nn < g * 512 + 512; ++nn)
        acc += p[nn] * bf2f(v[((size_t)(b * 4096) + nn) * 256 + h * 32 + d]);
    pv[tid] = acc; __syncthreads();
    if (tid < 32) {
        float t = 0.f;
        #pragma unroll
        for (int gg = 0; gg < 8; ++gg) t += pv[gg * 32 + tid];
        agent_v[(((size_t)(b * 8) + h) * 49 + a) * 32 + tid] = t * inv;
    }
}

// ---------------------------------------------------------------------------
// K5: stage-2 attention (49-way softmax per query) + fused depthwise 3x3 conv.
// One thread per (b,h,pos).  grid (128, 16), block 256.
// ---------------------------------------------------------------------------
__global__ __launch_bounds__(256) void stage2(
    const bf16* __restrict__ q, const bf16* __restrict__ v,
    const float* __restrict__ agent, const float* __restrict__ agent_v,
    const float* __restrict__ abias, const float* __restrict__ wdwc,
    const float* __restrict__ bdwc, bf16* __restrict__ mid)
{
    int bh = blockIdx.x;
    int b = bh >> 3, h = bh & 7;
    int pos0 = blockIdx.y * 256;
    __shared__ float ag[49 * 32];
    __shared__ float av[49 * 32];
    __shared__ float sab[256 * 49];
    __shared__ float wd[32 * 9];
    __shared__ float bd[32];
    int tid = threadIdx.x;
    for (int i = tid; i < 1568; i += 256) {
        ag[i] = agent[((size_t)(b * 49) + (i >> 5)) * 256 + h * 32 + (i & 31)];
        av[i] = agent_v[(((size_t)(b * 8) + h) * 49) * 32 + i];
    }
    for (int i = tid; i < 256 * 49; i += 256)
        sab[i] = abias[((size_t)(h * 4096) + pos0) * 49 + i];
    if (tid < 32) {
        #pragma unroll
        for (int j = 0; j < 9; ++j) wd[tid * 9 + j] = wdwc[(h * 32 + tid) * 9 + j];
        bd[tid] = bdwc[h * 32 + tid];
    }
    __syncthreads();

    int pos = pos0 + tid;
    float qv[32];
    {
        const bf16* qr = q + ((size_t)(b * 4096) + pos) * 256 + h * 32;
        #pragma unroll
        for (int u = 0; u < 4; ++u) {
            float f[8]; load8bf(qr + u * 8, f);
            #pragma unroll
            for (int d = 0; d < 8; ++d) qv[u * 8 + d] = f[d] * SCALE;
        }
    }
    float s[49];
    float m = -1e30f;
    #pragma unroll
    for (int a = 0; a < 49; ++a) {
        float t = sab[tid * 49 + a];
        #pragma unroll
        for (int d = 0; d < 32; ++d) t += qv[d] * ag[a * 32 + d];
        s[a] = t; m = fmaxf(m, t);
    }
    float sum = 0.f;
    #pragma unroll
    for (int a = 0; a < 49; ++a) { float e = __expf(s[a] - m); s[a] = e; sum += e; }
    float inv = 1.f / sum;
    float acc[32];
    #pragma unroll
    for (int d = 0; d < 32; ++d) acc[d] = 0.f;
    #pragma unroll
    for (int a = 0; a < 49; ++a) {
        float pa = s[a] * inv;
        #pragma unroll
        for (int d = 0; d < 32; ++d) acc[d] += pa * av[a * 32 + d];
    }
    // fused depthwise 3x3 conv on v (zero pad), channels h*32..h*32+31
    int y = pos >> 6, x = pos & 63;
    #pragma unroll
    for (int dy = -1; dy <= 1; ++dy) {
        int yy = y + dy; if (yy < 0 || yy > 63) continue;
        #pragma unroll
        for (int dx = -1; dx <= 1; ++dx) {
            int xx = x + dx; if (xx < 0 || xx > 63) continue;
            const bf16* vr = v + ((size_t)(b * 4096) + yy * 64 + xx) * 256 + h * 32;
            int widx = (dy + 1) * 3 + (dx + 1);
            #pragma unroll
            for (int u = 0; u < 4; ++u) {
                float f[8]; load8bf(vr + u * 8, f);
                #pragma unroll
                for (int d = 0; d < 8; ++d) acc[u * 8 + d] += wd[(u * 8 + d) * 9 + widx] * f[d];
            }
        }
    }
    #pragma unroll
    for (int d = 0; d < 32; ++d) acc[d] += bd[d];

    bf16* dst = mid + ((size_t)(b * 4096) + pos) * 256 + h * 32;
    #pragma unroll
    for (int u = 0; u < 4; ++u) {
        ushort4 w;
        w.x = f2bf(acc[u * 8 + 0] * 1.0f + 0.0f);
        w.x = f2bf(acc[u * 8 + 0]);
        w.y = f2bf(acc[u * 8 + 1]);
        w.z = f2bf(acc[u * 8 + 2]);
        w.w = f2bf(acc[u * 8 + 3]);
        ushort4 w2;
        w2.x = f2bf(acc[u * 8 + 4]);
        w2.y = f2bf(acc[u * 8 + 5]);
        w2.z = f2bf(acc[u * 8 + 6]);
        w2.w = f2bf(acc[u * 8 + 7]);
        *reinterpret_cast<ushort4*>(dst + u * 8)     = w;
        *reinterpret_cast<ushort4*>(dst + u * 8 + 4) = w2;
    }
}

// ---------------------------------------------------------------------------
// K7: out[b][j][pos] = mid[b][pos][:] @ Wproj[j][:] + bproj[j]  (transposed store)
// grid (1024, 4), block 256.  64x64 tile, BK=16, 4x4 per thread.  Wp/bp/out fp32.
// ---------------------------------------------------------------------------
__global__ __launch_bounds__(256) void proj_gemm(
    const bf16* __restrict__ mid, const float* __restrict__ Wp,
    const float* __restrict__ bp, float* __restrict__ out)
{
    __shared__ float As[16][65];
    __shared__ float Bs[16][65];
    const int m0 = blockIdx.x * 64;
    const int j0 = blockIdx.y * 64;
    const int b = m0 >> 12;
    const int pos0 = m0 & 4095;
    const int tid = threadIdx.x;
    const int a_mm = tid >> 2, a_kb = (tid & 3) * 4;
    const int tx = tid & 15, ty = tid >> 4;   // tx -> pos dir, ty -> col dir
    float acc[4][4] = {};

    for (int k0 = 0; k0 < 256; k0 += 16) {
        {
            const bf16* ap = mid + ((size_t)m0 + a_mm) * 256 + k0 + a_kb;
            uint2 uu = *reinterpret_cast<const uint2*>(ap);
            As[a_kb + 0][a_mm] = __uint_as_float(uu.x << 16);
            As[a_kb + 1][a_mm] = __uint_as_float(uu.x & 0xffff0000u);
            As[a_kb + 2][a_mm] = __uint_as_float(uu.y << 16);
            As[a_kb + 3][a_mm] = __uint_as_float(uu.y & 0xffff0000u);
        }
        {
            const float4 w4 = *reinterpret_cast<const float4*>(
                Wp + (size_t)(j0 + a_mm) * 256 + k0 + a_kb);
            Bs[a_kb + 0][a_mm] = w4.x;
            Bs[a_kb + 1][a_mm] = w4.y;
            Bs[a_kb + 2][a_mm] = w4.z;
            Bs[a_kb + 3][a_mm] = w4.w;
        }
        __syncthreads();
        #pragma unroll
        for (int kk = 0; kk < 16; ++kk) {
            float avr[4], bvr[4];
            #pragma unroll
            for (int i = 0; i < 4; ++i) avr[i] = As[kk][tx * 4 + i];
            #pragma unroll
            for (int j = 0; j < 4; ++j) bvr[j] = Bs[kk][ty * 4 + j];
            #pragma unroll
            for (int i = 0; i < 4; ++i)
                #pragma unroll
                for (int j = 0; j < 4; ++j) acc[i][j] += avr[i] * bvr[j];
        }
        __syncthreads();
    }
    // transposed store: out[(b*256+col)*4096 + pos], 4 consecutive pos = 16B
    #pragma unroll
    for (int j = 0; j < 4; ++j) {
        int col = j0 + ty * 4 + j;
        float bias = bp[col];
        float4 w;
        w.x = acc[0][j] + bias; w.y = acc[1][j] + bias;
        w.z = acc[2][j] + bias; w.w = acc[3][j] + bias;
        *reinterpret_cast<float4*>(out + ((size_t)(b * 256) + col) * 4096 + pos0 + tx * 4) = w;
    }
}

extern "C" void kernel_launch(void* const* d_in, const int* in_sizes, int n_in,
                              void* d_out, int out_size, void* d_ws, size_t ws_size,
                              hipStream_t stream)
{
    const float* x       = (const float*)d_in[0];
    const float* Wq      = (const float*)d_in[1];
    const float* Wkv     = (const float*)d_in[2];
    const float* Wproj   = (const float*)d_in[3];
    const float* bproj   = (const float*)d_in[4];
    const float* Wdwc    = (const float*)d_in[5];
    const float* bdwc    = (const float*)d_in[6];
    const float* an_bias = (const float*)d_in[7];
    const float* na_bias = (const float*)d_in[8];
    const float* ah_bias = (const float*)d_in[9];
    const float* aw_bias = (const float*)d_in[10];
    const float* ha_bias = (const float*)d_in[11];
    const float* wa_bias = (const float*)d_in[12];
    // H=64, W=64 hard-coded (d_in[13], d_in[14])

    char* ws = (char*)d_ws;
    bf16*  q      = (bf16*)(ws + 0);
    bf16*  k      = (bf16*)(ws + 33554432);
    bf16*  v      = (bf16*)(ws + 67108864);
    bf16*  mid    = (bf16*)(ws + 100663296);
    float* agent  = (float*)(ws + 134217728);
    float* agentv = (float*)(ws + 135020544);
    float* pbias  = (float*)(ws + 135823360);
    float* abias  = (float*)(ws + 142245888);
    float* out    = (float*)d_out;

    qkv_gemm <<<dim3(1024, 12), 256, 0, stream>>>(x, Wq, Wkv, q, k, v);
    pool_agent<<<dim3(784),     256, 0, stream>>>(q, agent);
    make_pbias<<<dim3(392),     256, 0, stream>>>(an_bias, ah_bias, aw_bias, pbias);
    make_abias<<<dim3(392),     256, 0, stream>>>(na_bias, ha_bias, wa_bias, abias);
    stage1    <<<dim3(6272),    256, 0, stream>>>(agent, k, v, pbias, agentv);
    stage2    <<<dim3(128, 16), 256, 0, stream>>>(q, v, agent, agentv, abias, Wdwc, bdwc, mid);
    proj_gemm <<<dim3(1024, 4), 256, 0, stream>>>(mid, Wproj, bproj, out);
}

// Round 3
// 1075.904 us; speedup vs baseline: 1.5470x; 1.5470x over previous
//
#include <hip/hip_runtime.h>
#include <hip/hip_bf16.h>
#include <stdint.h>

using bf16 = __hip_bfloat16;

#define SCALE 0.17677669529663687f   // 32^-0.5

__device__ __forceinline__ float bf2f(bf16 v) { return __bfloat162float(v); }

__device__ __forceinline__ unsigned short f2bf(float f) {
    unsigned int u = __float_as_uint(f);
    unsigned int r = u + 0x7fffu + ((u >> 16) & 1u);   // RNE; inputs never NaN/Inf
    return (unsigned short)(r >> 16);
}

// load 8 consecutive bf16 (16B-aligned) -> 8 floats
__device__ __forceinline__ void load8bf(const bf16* p, float* f) {
    uint4 u = *reinterpret_cast<const uint4*>(p);
    f[0] = __uint_as_float(u.x << 16); f[1] = __uint_as_float(u.x & 0xffff0000u);
    f[2] = __uint_as_float(u.y << 16); f[3] = __uint_as_float(u.y & 0xffff0000u);
    f[4] = __uint_as_float(u.z << 16); f[5] = __uint_as_float(u.z & 0xffff0000u);
    f[6] = __uint_as_float(u.w << 16); f[7] = __uint_as_float(u.w & 0xffff0000u);
}

// ---------------------------------------------------------------------------
// K1: q/k/v = xt @ [Wq;Wkv]^T.  A[m][kk] = x[b][kk][pos] (transposed read).
// M=65536, K=256, N=768.  grid (1024, 12), block 256.
// ---------------------------------------------------------------------------
__global__ __launch_bounds__(256) void qkv_gemm(
    const float* __restrict__ x, const float* __restrict__ Wq,
    const float* __restrict__ Wkv,
    bf16* __restrict__ q, bf16* __restrict__ k, bf16* __restrict__ v)
{
    __shared__ float As[16][65];
    __shared__ float Bs[16][65];
    const int m0 = blockIdx.x * 64;
    const int j0 = blockIdx.y * 64;           // 0..767
    const int b = m0 >> 12;
    const int pos0 = m0 & 4095;
    const float* Wbase; int jb;
    if (j0 < 256) { Wbase = Wq;  jb = j0; }
    else          { Wbase = Wkv; jb = j0 - 256; }
    const int tid = threadIdx.x;
    const int a_mm = tid & 63, a_kb = tid >> 6;      // A loader
    const int b_jj = tid >> 2, b_kb = (tid & 3) * 4; // B loader
    const int tx = tid & 15, ty = tid >> 4;
    float acc[4][4] = {};

    for (int k0 = 0; k0 < 256; k0 += 16) {
        #pragma unroll
        for (int u = 0; u < 4; ++u) {
            int kk = a_kb + 4 * u;
            As[kk][a_mm] = x[((size_t)(b * 256 + k0 + kk)) * 4096 + pos0 + a_mm];
        }
        {
            const float4 w4 = *reinterpret_cast<const float4*>(
                Wbase + (size_t)(jb + b_jj) * 256 + k0 + b_kb);
            Bs[b_kb + 0][b_jj] = w4.x;
            Bs[b_kb + 1][b_jj] = w4.y;
            Bs[b_kb + 2][b_jj] = w4.z;
            Bs[b_kb + 3][b_jj] = w4.w;
        }
        __syncthreads();
        #pragma unroll
        for (int kk = 0; kk < 16; ++kk) {
            float av[4], bv[4];
            #pragma unroll
            for (int i = 0; i < 4; ++i) av[i] = As[kk][ty * 4 + i];
            #pragma unroll
            for (int j = 0; j < 4; ++j) bv[j] = Bs[kk][tx * 4 + j];
            #pragma unroll
            for (int i = 0; i < 4; ++i)
                #pragma unroll
                for (int j = 0; j < 4; ++j) acc[i][j] += av[i] * bv[j];
        }
        __syncthreads();
    }
    bf16* dst; int cb;
    if (j0 < 256)      { dst = q; cb = j0; }
    else if (j0 < 512) { dst = k; cb = j0 - 256; }
    else               { dst = v; cb = j0 - 512; }
    #pragma unroll
    for (int i = 0; i < 4; ++i) {
        int pos = pos0 + ty * 4 + i;
        ushort4 w;
        w.x = f2bf(acc[i][0]); w.y = f2bf(acc[i][1]);
        w.z = f2bf(acc[i][2]); w.w = f2bf(acc[i][3]);
        *reinterpret_cast<ushort4*>(dst + ((size_t)(b * 4096 + pos)) * 256 + cb + tx * 4) = w;
    }
}

// ---------------------------------------------------------------------------
// K2: agent tokens = adaptive avg pool 64x64 -> 7x7 of q.  grid 784, block 256.
// ---------------------------------------------------------------------------
__global__ __launch_bounds__(256) void pool_agent(
    const bf16* __restrict__ q, float* __restrict__ agent)
{
    int bid = blockIdx.x;
    int b = bid / 49, a = bid % 49;
    int py = a / 7, px = a % 7;
    int ys = (py * 64) / 7, ye = ((py + 1) * 64 + 6) / 7;
    int xs = (px * 64) / 7, xe = ((px + 1) * 64 + 6) / 7;
    int ch = threadIdx.x;
    float s = 0.f;
    for (int y = ys; y < ye; ++y)
        for (int x = xs; x < xe; ++x)
            s += bf2f(q[((size_t)(b * 4096) + y * 64 + x) * 256 + ch]);
    agent[((size_t)(b * 49) + a) * 256 + ch] = s / (float)((ye - ys) * (xe - xs));
}

// ---------------------------------------------------------------------------
// K3a: pbias[h][a][pos] (bilerp + ah + aw).  grid 392, block 256.
// ---------------------------------------------------------------------------
__global__ __launch_bounds__(256) void make_pbias(
    const float* __restrict__ an, const float* __restrict__ ahb,
    const float* __restrict__ awb, float* __restrict__ pbias)
{
    int bid = blockIdx.x;               // h*49 + a
    __shared__ float bb[49], ay[64], ax[64];
    int tid = threadIdx.x;
    if (tid < 49) bb[tid] = an[(size_t)bid * 49 + tid];
    if (tid < 64) {
        ay[tid] = ahb[(size_t)bid * 64 + tid];
        ax[tid] = awb[(size_t)bid * 64 + tid];
    }
    __syncthreads();
    for (int it = 0; it < 16; ++it) {
        int pos = it * 256 + tid;
        int y = pos >> 6, x = pos & 63;
        float fy = (y + 0.5f) * (7.f / 64.f) - 0.5f; fy = fminf(fmaxf(fy, 0.f), 6.f);
        float fx = (x + 0.5f) * (7.f / 64.f) - 0.5f; fx = fminf(fmaxf(fx, 0.f), 6.f);
        int y0 = (int)fy, x0 = (int)fx;
        int y1 = min(y0 + 1, 6), x1 = min(x0 + 1, 6);
        float wy = fy - y0, wx = fx - x0;
        float val = (1.f - wy) * ((1.f - wx) * bb[y0 * 7 + x0] + wx * bb[y0 * 7 + x1])
                  + wy * ((1.f - wx) * bb[y1 * 7 + x0] + wx * bb[y1 * 7 + x1]);
        pbias[(size_t)bid * 4096 + pos] = val + ay[y] + ax[x];
    }
}

// ---------------------------------------------------------------------------
// K3b: abias[h][pos][a] (bilerp + ha + wa).  grid 392, block 256.
// ---------------------------------------------------------------------------
__global__ __launch_bounds__(256) void make_abias(
    const float* __restrict__ na, const float* __restrict__ hab,
    const float* __restrict__ wab, float* __restrict__ abias)
{
    int bid = blockIdx.x;
    int h = bid / 49, a = bid % 49;
    __shared__ float bb[49], hy[64], wx_[64];
    int tid = threadIdx.x;
    if (tid < 49) bb[tid] = na[(size_t)bid * 49 + tid];
    if (tid < 64) {
        hy[tid]  = hab[((size_t)(h * 64) + tid) * 49 + a];
        wx_[tid] = wab[((size_t)(h * 64) + tid) * 49 + a];
    }
    __syncthreads();
    for (int it = 0; it < 16; ++it) {
        int pos = it * 256 + tid;
        int y = pos >> 6, x = pos & 63;
        float fy = (y + 0.5f) * (7.f / 64.f) - 0.5f; fy = fminf(fmaxf(fy, 0.f), 6.f);
        float fx = (x + 0.5f) * (7.f / 64.f) - 0.5f; fx = fminf(fmaxf(fx, 0.f), 6.f);
        int y0 = (int)fy, x0 = (int)fx;
        int y1 = min(y0 + 1, 6), x1 = min(x0 + 1, 6);
        float wy = fy - y0, wxv = fx - x0;
        float val = (1.f - wy) * ((1.f - wxv) * bb[y0 * 7 + x0] + wxv * bb[y0 * 7 + x1])
                  + wy * ((1.f - wxv) * bb[y1 * 7 + x0] + wxv * bb[y1 * 7 + x1]);
        abias[((size_t)(h * 4096) + pos) * 49 + a] = val + hy[y] + wx_[x];
    }
}

// ---------------------------------------------------------------------------
// K4: stage-1 attention, restructured.
// Scores are tiny (|s| < ~1) => exp without max subtraction is exact enough,
// making softmax LINEAR in partials: O = sum(e*v), Z = sum(e), divide at end.
// One block per (b, h, n-split of 512).  grid 1024 (=16*8*8), block 256.
//  - score: thread-per-n, k in VGPRs, agent-q via wave-uniform SGPR loads.
//  - PV:    wave w owns d in [8w,8w+8), lane = agent; v rows via SGPR loads;
//           only per-lane LDS traffic = one b32 e-read per nn (feeds 8 FMA).
// Partials go into the (not-yet-used) `mid` region of ws.
// ---------------------------------------------------------------------------
#define S1_SPLIT 8
__global__ __launch_bounds__(256) void stage1(
    const float* __restrict__ agent, const bf16* __restrict__ k,
    const bf16* __restrict__ v, const float* __restrict__ pbias,
    float* __restrict__ part_O, float* __restrict__ part_sum)
{
    const int bid = blockIdx.x;
    const int split = bid & 7, h = (bid >> 3) & 7, b = bid >> 6;
    const int tid = threadIdx.x;
    __shared__ float e_lds[64 * 129];   // [a][n_loc], stride 129: <=2-way conflicts

    const int n_loc = tid & 127;
    const int half  = __builtin_amdgcn_readfirstlane(tid >> 7);  // wave-uniform
    const int a0 = half * 25, na = half ? 24 : 25;
    const int wv   = __builtin_amdgcn_readfirstlane(tid >> 6);   // wave id 0..3
    const int lane = tid & 63;
    const int aL = lane < 49 ? lane : 48;

    float o[8] = {0.f, 0.f, 0.f, 0.f, 0.f, 0.f, 0.f, 0.f};
    float sacc = 0.f;

    for (int tile = 0; tile < 4; ++tile) {
        const int nbase = split * 512 + tile * 128;
        __syncthreads();                       // e_lds free from previous tile
        // ---- score phase ----
        {
            const int n_glob = nbase + n_loc;
            float kf[32];
            const bf16* kr = k + ((size_t)(b * 4096) + n_glob) * 256 + h * 32;
            load8bf(kr, kf); load8bf(kr + 8, kf + 8);
            load8bf(kr + 16, kf + 16); load8bf(kr + 24, kf + 24);
            const float* aqb = agent + ((size_t)(b * 49) + a0) * 256 + h * 32;
            const float* pbb = pbias + ((size_t)(h * 49) + a0) * 4096 + n_glob;
            for (int ai = 0; ai < na; ++ai) {
                const float* aq = aqb + (size_t)ai * 256;   // wave-uniform addr
                float dot = 0.f;
                #pragma unroll
                for (int d = 0; d < 32; ++d) dot = fmaf(aq[d], kf[d], dot);
                float s = dot * SCALE + pbb[(size_t)ai * 4096];
                e_lds[(a0 + ai) * 129 + n_loc] = __expf(s);
            }
        }
        __syncthreads();                       // e_lds ready
        // ---- PV phase ----
        {
            const uint4* vrow = reinterpret_cast<const uint4*>(
                v + ((size_t)(b * 4096) + nbase) * 256 + h * 32 + wv * 8);
            for (int nn = 0; nn < 128; ++nn) {
                float e = e_lds[aL * 129 + nn];
                uint4 pk = vrow[(size_t)nn * 32];            // wave-uniform addr
                float vf[8];
                vf[0] = __uint_as_float(pk.x << 16); vf[1] = __uint_as_float(pk.x & 0xffff0000u);
                vf[2] = __uint_as_float(pk.y << 16); vf[3] = __uint_as_float(pk.y & 0xffff0000u);
                vf[4] = __uint_as_float(pk.z << 16); vf[5] = __uint_as_float(pk.z & 0xffff0000u);
                vf[6] = __uint_as_float(pk.w << 16); vf[7] = __uint_as_float(pk.w & 0xffff0000u);
                #pragma unroll
                for (int j = 0; j < 8; ++j) o[j] = fmaf(e, vf[j], o[j]);
                sacc += e;
            }
        }
    }
    if (lane < 49) {
        float* dst = part_O + ((size_t)((b * 8 + h) * 8 + split)) * 1568 + lane * 32 + wv * 8;
        float4 w0 = make_float4(o[0], o[1], o[2], o[3]);
        float4 w1 = make_float4(o[4], o[5], o[6], o[7]);
        *reinterpret_cast<float4*>(dst)     = w0;
        *reinterpret_cast<float4*>(dst + 4) = w1;
        if (wv == 0)
            part_sum[((b * 8 + h) * 8 + split) * 49 + lane] = sacc;
    }
}

// K4b: combine split partials.  grid 128 (b*8+h), block 256.
__global__ __launch_bounds__(256) void stage1_fin(
    const float* __restrict__ part_O, const float* __restrict__ part_sum,
    float* __restrict__ agent_v)
{
    int bh = blockIdx.x;
    __shared__ float inv[49];
    int tid = threadIdx.x;
    if (tid < 49) {
        float s = 0.f;
        #pragma unroll
        for (int sp = 0; sp < 8; ++sp) s += part_sum[(bh * 8 + sp) * 49 + tid];
        inv[tid] = 1.f / s;
    }
    __syncthreads();
    for (int idx = tid; idx < 1568; idx += 256) {
        float o = 0.f;
        #pragma unroll
        for (int sp = 0; sp < 8; ++sp) o += part_O[((size_t)(bh * 8) + sp) * 1568 + idx];
        agent_v[(size_t)bh * 1568 + idx] = o * inv[idx >> 5];
    }
}

// ---------------------------------------------------------------------------
// K5: stage-2 attention (49-way softmax per query) + fused depthwise 3x3 conv.
// One thread per (b,h,pos).  grid (128, 16), block 256.
// ---------------------------------------------------------------------------
__global__ __launch_bounds__(256) void stage2(
    const bf16* __restrict__ q, const bf16* __restrict__ v,
    const float* __restrict__ agent, const float* __restrict__ agent_v,
    const float* __restrict__ abias, const float* __restrict__ wdwc,
    const float* __restrict__ bdwc, bf16* __restrict__ mid)
{
    int bh = blockIdx.x;
    int b = bh >> 3, h = bh & 7;
    int pos0 = blockIdx.y * 256;
    __shared__ float ag[49 * 32];
    __shared__ float av[49 * 32];
    __shared__ float sab[256 * 49];
    __shared__ float wd[32 * 9];
    __shared__ float bd[32];
    int tid = threadIdx.x;
    for (int i = tid; i < 1568; i += 256) {
        ag[i] = agent[((size_t)(b * 49) + (i >> 5)) * 256 + h * 32 + (i & 31)];
        av[i] = agent_v[(((size_t)(b * 8) + h) * 49) * 32 + i];
    }
    for (int i = tid; i < 256 * 49; i += 256)
        sab[i] = abias[((size_t)(h * 4096) + pos0) * 49 + i];
    if (tid < 32) {
        #pragma unroll
        for (int j = 0; j < 9; ++j) wd[tid * 9 + j] = wdwc[(h * 32 + tid) * 9 + j];
        bd[tid] = bdwc[h * 32 + tid];
    }
    __syncthreads();

    int pos = pos0 + tid;
    float qv[32];
    {
        const bf16* qr = q + ((size_t)(b * 4096) + pos) * 256 + h * 32;
        #pragma unroll
        for (int u = 0; u < 4; ++u) {
            float f[8]; load8bf(qr + u * 8, f);
            #pragma unroll
            for (int d = 0; d < 8; ++d) qv[u * 8 + d] = f[d] * SCALE;
        }
    }
    float s[49];
    float m = -1e30f;
    #pragma unroll
    for (int a = 0; a < 49; ++a) {
        float t = sab[tid * 49 + a];
        #pragma unroll
        for (int d = 0; d < 32; ++d) t += qv[d] * ag[a * 32 + d];
        s[a] = t; m = fmaxf(m, t);
    }
    float sum = 0.f;
    #pragma unroll
    for (int a = 0; a < 49; ++a) { float e = __expf(s[a] - m); s[a] = e; sum += e; }
    float inv = 1.f / sum;
    float acc[32];
    #pragma unroll
    for (int d = 0; d < 32; ++d) acc[d] = 0.f;
    #pragma unroll
    for (int a = 0; a < 49; ++a) {
        float pa = s[a] * inv;
        #pragma unroll
        for (int d = 0; d < 32; ++d) acc[d] += pa * av[a * 32 + d];
    }
    // fused depthwise 3x3 conv on v (zero pad), channels h*32..h*32+31
    int y = pos >> 6, x = pos & 63;
    #pragma unroll
    for (int dy = -1; dy <= 1; ++dy) {
        int yy = y + dy; if (yy < 0 || yy > 63) continue;
        #pragma unroll
        for (int dx = -1; dx <= 1; ++dx) {
            int xx = x + dx; if (xx < 0 || xx > 63) continue;
            const bf16* vr = v + ((size_t)(b * 4096) + yy * 64 + xx) * 256 + h * 32;
            int widx = (dy + 1) * 3 + (dx + 1);
            #pragma unroll
            for (int u = 0; u < 4; ++u) {
                float f[8]; load8bf(vr + u * 8, f);
                #pragma unroll
                for (int d = 0; d < 8; ++d) acc[u * 8 + d] += wd[(u * 8 + d) * 9 + widx] * f[d];
            }
        }
    }
    #pragma unroll
    for (int d = 0; d < 32; ++d) acc[d] += bd[d];

    bf16* dst = mid + ((size_t)(b * 4096) + pos) * 256 + h * 32;
    #pragma unroll
    for (int u = 0; u < 4; ++u) {
        ushort4 w;
        w.x = f2bf(acc[u * 8 + 0]);
        w.y = f2bf(acc[u * 8 + 1]);
        w.z = f2bf(acc[u * 8 + 2]);
        w.w = f2bf(acc[u * 8 + 3]);
        ushort4 w2;
        w2.x = f2bf(acc[u * 8 + 4]);
        w2.y = f2bf(acc[u * 8 + 5]);
        w2.z = f2bf(acc[u * 8 + 6]);
        w2.w = f2bf(acc[u * 8 + 7]);
        *reinterpret_cast<ushort4*>(dst + u * 8)     = w;
        *reinterpret_cast<ushort4*>(dst + u * 8 + 4) = w2;
    }
}

// ---------------------------------------------------------------------------
// K7: out[b][j][pos] = mid[b][pos][:] @ Wproj[j][:] + bproj[j]  (transposed store)
// grid (1024, 4), block 256.
// ---------------------------------------------------------------------------
__global__ __launch_bounds__(256) void proj_gemm(
    const bf16* __restrict__ mid, const float* __restrict__ Wp,
    const float* __restrict__ bp, float* __restrict__ out)
{
    __shared__ float As[16][65];
    __shared__ float Bs[16][65];
    const int m0 = blockIdx.x * 64;
    const int j0 = blockIdx.y * 64;
    const int b = m0 >> 12;
    const int pos0 = m0 & 4095;
    const int tid = threadIdx.x;
    const int a_mm = tid >> 2, a_kb = (tid & 3) * 4;
    const int tx = tid & 15, ty = tid >> 4;   // tx -> pos dir, ty -> col dir
    float acc[4][4] = {};

    for (int k0 = 0; k0 < 256; k0 += 16) {
        {
            const bf16* ap = mid + ((size_t)m0 + a_mm) * 256 + k0 + a_kb;
            uint2 uu = *reinterpret_cast<const uint2*>(ap);
            As[a_kb + 0][a_mm] = __uint_as_float(uu.x << 16);
            As[a_kb + 1][a_mm] = __uint_as_float(uu.x & 0xffff0000u);
            As[a_kb + 2][a_mm] = __uint_as_float(uu.y << 16);
            As[a_kb + 3][a_mm] = __uint_as_float(uu.y & 0xffff0000u);
        }
        {
            const float4 w4 = *reinterpret_cast<const float4*>(
                Wp + (size_t)(j0 + a_mm) * 256 + k0 + a_kb);
            Bs[a_kb + 0][a_mm] = w4.x;
            Bs[a_kb + 1][a_mm] = w4.y;
            Bs[a_kb + 2][a_mm] = w4.z;
            Bs[a_kb + 3][a_mm] = w4.w;
        }
        __syncthreads();
        #pragma unroll
        for (int kk = 0; kk < 16; ++kk) {
            float avr[4], bvr[4];
            #pragma unroll
            for (int i = 0; i < 4; ++i) avr[i] = As[kk][tx * 4 + i];
            #pragma unroll
            for (int j = 0; j < 4; ++j) bvr[j] = Bs[kk][ty * 4 + j];
            #pragma unroll
            for (int i = 0; i < 4; ++i)
                #pragma unroll
                for (int j = 0; j < 4; ++j) acc[i][j] += avr[i] * bvr[j];
        }
        __syncthreads();
    }
    #pragma unroll
    for (int j = 0; j < 4; ++j) {
        int col = j0 + ty * 4 + j;
        float bias = bp[col];
        float4 w;
        w.x = acc[0][j] + bias; w.y = acc[1][j] + bias;
        w.z = acc[2][j] + bias; w.w = acc[3][j] + bias;
        *reinterpret_cast<float4*>(out + ((size_t)(b * 256) + col) * 4096 + pos0 + tx * 4) = w;
    }
}

extern "C" void kernel_launch(void* const* d_in, const int* in_sizes, int n_in,
                              void* d_out, int out_size, void* d_ws, size_t ws_size,
                              hipStream_t stream)
{
    const float* x       = (const float*)d_in[0];
    const float* Wq      = (const float*)d_in[1];
    const float* Wkv     = (const float*)d_in[2];
    const float* Wproj   = (const float*)d_in[3];
    const float* bproj   = (const float*)d_in[4];
    const float* Wdwc    = (const float*)d_in[5];
    const float* bdwc    = (const float*)d_in[6];
    const float* an_bias = (const float*)d_in[7];
    const float* na_bias = (const float*)d_in[8];
    const float* ah_bias = (const float*)d_in[9];
    const float* aw_bias = (const float*)d_in[10];
    const float* ha_bias = (const float*)d_in[11];
    const float* wa_bias = (const float*)d_in[12];
    // H=64, W=64 hard-coded (d_in[13], d_in[14])

    char* ws = (char*)d_ws;
    bf16*  q      = (bf16*)(ws + 0);
    bf16*  k      = (bf16*)(ws + 33554432);
    bf16*  v      = (bf16*)(ws + 67108864);
    bf16*  mid    = (bf16*)(ws + 100663296);
    float* agent  = (float*)(ws + 134217728);
    float* agentv = (float*)(ws + 135020544);
    float* pbias  = (float*)(ws + 135823360);
    float* abias  = (float*)(ws + 142245888);
    // stage1 partials alias the `mid` region (mid written only later, by stage2):
    float* part_O   = (float*)(ws + 100663296);              // 6.42 MB
    float* part_sum = (float*)(ws + 100663296 + 6422528);    // 0.20 MB
    float* out    = (float*)d_out;

    qkv_gemm  <<<dim3(1024, 12), 256, 0, stream>>>(x, Wq, Wkv, q, k, v);
    pool_agent<<<dim3(784),      256, 0, stream>>>(q, agent);
    make_pbias<<<dim3(392),      256, 0, stream>>>(an_bias, ah_bias, aw_bias, pbias);
    make_abias<<<dim3(392),      256, 0, stream>>>(na_bias, ha_bias, wa_bias, abias);
    stage1    <<<dim3(1024),     256, 0, stream>>>(agent, k, v, pbias, part_O, part_sum);
    stage1_fin<<<dim3(128),      256, 0, stream>>>(part_O, part_sum, agentv);
    stage2    <<<dim3(128, 16),  256, 0, stream>>>(q, v, agent, agentv, abias, Wdwc, bdwc, mid);
    proj_gemm <<<dim3(1024, 4),  256, 0, stream>>>(mid, Wproj, bproj, out);
}

// Round 4
// 550.335 us; speedup vs baseline: 3.0244x; 1.9550x over previous
//
#include <hip/hip_runtime.h>
#include <hip/hip_bf16.h>
#include <stdint.h>

using bf16 = __hip_bfloat16;

#define SCALE 0.17677669529663687f   // 32^-0.5

typedef short short8 __attribute__((ext_vector_type(8)));
typedef float f32x4 __attribute__((ext_vector_type(4)));

__device__ __forceinline__ float bf2f(bf16 v) { return __bfloat162float(v); }

__device__ __forceinline__ unsigned short f2bf(float f) {
    unsigned int u = __float_as_uint(f);
    unsigned int r = u + 0x7fffu + ((u >> 16) & 1u);   // RNE; inputs never NaN/Inf
    return (unsigned short)(r >> 16);
}

// load 8 consecutive bf16 (16B-aligned) -> 8 floats
__device__ __forceinline__ void load8bf(const bf16* p, float* f) {
    uint4 u = *reinterpret_cast<const uint4*>(p);
    f[0] = __uint_as_float(u.x << 16); f[1] = __uint_as_float(u.x & 0xffff0000u);
    f[2] = __uint_as_float(u.y << 16); f[3] = __uint_as_float(u.y & 0xffff0000u);
    f[4] = __uint_as_float(u.z << 16); f[5] = __uint_as_float(u.z & 0xffff0000u);
    f[6] = __uint_as_float(u.w << 16); f[7] = __uint_as_float(u.w & 0xffff0000u);
}

__device__ __forceinline__ void gload16(const void* g, void* l) {
    __builtin_amdgcn_global_load_lds(
        (const __attribute__((address_space(1))) void*)g,
        (__attribute__((address_space(3))) void*)l, 16, 0, 0);
}

// ---------------------------------------------------------------------------
// K0a: convert weights to bf16.  rows 0..767 -> Wqkv (Wq then Wkv), 768..1023
// -> Wproj.  grid 1024, block 256.
// ---------------------------------------------------------------------------
__global__ __launch_bounds__(256) void convert_w(
    const float* __restrict__ Wq, const float* __restrict__ Wkv,
    const float* __restrict__ Wp,
    bf16* __restrict__ Wqkv_bf, bf16* __restrict__ Wp_bf)
{
    int row = blockIdx.x, tid = threadIdx.x;
    const float* src; bf16* dst;
    if (row < 768) {
        src = (row < 256) ? Wq + (size_t)row * 256 : Wkv + (size_t)(row - 256) * 256;
        dst = Wqkv_bf + (size_t)row * 256;
    } else {
        src = Wp + (size_t)(row - 768) * 256;
        dst = Wp_bf + (size_t)(row - 768) * 256;
    }
    *reinterpret_cast<unsigned short*>(dst + tid) = f2bf(src[tid]);
}

// ---------------------------------------------------------------------------
// K0b: xT[b][pos][c] = bf16(x[b][c][pos]).  64x64 LDS tile transpose.
// grid (64, 4, 16), block 256.
// ---------------------------------------------------------------------------
__global__ __launch_bounds__(256) void x_to_bf16T(
    const float* __restrict__ x, bf16* __restrict__ xT)
{
    __shared__ float t[64][65];
    const int b = blockIdx.z, pos0 = blockIdx.x * 64, c0 = blockIdx.y * 64;
    const int tid = threadIdx.x;
    const int cc = tid >> 6, p = tid & 63;
    #pragma unroll
    for (int i = 0; i < 16; ++i)
        t[cc + 4 * i][p] = x[((size_t)(b * 256 + c0 + cc + 4 * i)) * 4096 + pos0 + p];
    __syncthreads();
    const int pl = tid >> 2, qd = tid & 3;
    unsigned short tmp[16];
    #pragma unroll
    for (int j = 0; j < 16; ++j) tmp[j] = f2bf(t[qd * 16 + j][pl]);
    uint4* dst = reinterpret_cast<uint4*>(xT + ((size_t)(b * 4096 + pos0 + pl)) * 256 + c0 + qd * 16);
    dst[0] = reinterpret_cast<const uint4*>(tmp)[0];
    dst[1] = reinterpret_cast<const uint4*>(tmp)[1];
}

// ---------------------------------------------------------------------------
// K1: qkv MFMA GEMM.  D[m=pos][n=ch] = xT[b] (4096x256) . Wqkv^T (256x768).
// 128x128 tile, BK=32, 4 waves x (4x4 16x16x32 mfma).  grid (512, 6), block 256.
// ---------------------------------------------------------------------------
__global__ __launch_bounds__(256) void qkv_mfma(
    const bf16* __restrict__ xT, const bf16* __restrict__ Wqkv,
    bf16* __restrict__ q, bf16* __restrict__ k, bf16* __restrict__ v)
{
    __shared__ __align__(16) short As[128 * 32];
    __shared__ __align__(16) short Bs[128 * 32];
    const int b = blockIdx.x >> 5;
    const int m0 = (blockIdx.x & 31) * 128;
    const int j0 = blockIdx.y * 128;
    const int tid = threadIdx.x;
    const int w = tid >> 6, lane = tid & 63;
    const int wm = w & 1, wn = w >> 1;
    const int quad = lane >> 4, ln = lane & 15;

    const short* Ag = (const short*)xT + ((size_t)(b * 4096 + m0)) * 256;
    const short* Bg = (const short*)Wqkv + (size_t)j0 * 256;
    const int ldrow = lane >> 2;            // 0..15
    const int ldcol = (lane & 3) * 8;       // element offset within row

    f32x4 acc[4][4] = {};

    for (int k0 = 0; k0 < 256; k0 += 32) {
        __syncthreads();
        #pragma unroll
        for (int p = 0; p < 2; ++p) {
            int row = w * 32 + p * 16;
            gload16(Ag + (size_t)(row + ldrow) * 256 + k0 + ldcol, As + row * 32);
            gload16(Bg + (size_t)(row + ldrow) * 256 + k0 + ldcol, Bs + row * 32);
        }
        __syncthreads();
        short8 af[4], bfr[4];
        #pragma unroll
        for (int mi = 0; mi < 4; ++mi)
            af[mi] = *reinterpret_cast<const short8*>(&As[(wm * 64 + mi * 16 + ln) * 32 + quad * 8]);
        #pragma unroll
        for (int ni = 0; ni < 4; ++ni)
            bfr[ni] = *reinterpret_cast<const short8*>(&Bs[(wn * 64 + ni * 16 + ln) * 32 + quad * 8]);
        #pragma unroll
        for (int mi = 0; mi < 4; ++mi)
            #pragma unroll
            for (int ni = 0; ni < 4; ++ni)
                acc[mi][ni] = __builtin_amdgcn_mfma_f32_16x16x32_bf16(
                    af[mi], bfr[ni], acc[mi][ni], 0, 0, 0);
    }

    bf16* dst; int cb;
    if (j0 < 256)      { dst = q; cb = j0; }
    else if (j0 < 512) { dst = k; cb = j0 - 256; }
    else               { dst = v; cb = j0 - 512; }
    #pragma unroll
    for (int mi = 0; mi < 4; ++mi)
        #pragma unroll
        for (int r = 0; r < 4; ++r) {
            int pos = m0 + wm * 64 + mi * 16 + quad * 4 + r;
            unsigned short* o = reinterpret_cast<unsigned short*>(
                dst + ((size_t)(b * 4096 + pos)) * 256 + cb + wn * 64 + ln);
            #pragma unroll
            for (int ni = 0; ni < 4; ++ni)
                o[ni * 16] = f2bf(acc[mi][ni][r]);
        }
}

// ---------------------------------------------------------------------------
// K2: agent tokens = adaptive avg pool 64x64 -> 7x7 of q.  grid 784, block 256.
// ---------------------------------------------------------------------------
__global__ __launch_bounds__(256) void pool_agent(
    const bf16* __restrict__ q, float* __restrict__ agent)
{
    int bid = blockIdx.x;
    int b = bid / 49, a = bid % 49;
    int py = a / 7, px = a % 7;
    int ys = (py * 64) / 7, ye = ((py + 1) * 64 + 6) / 7;
    int xs = (px * 64) / 7, xe = ((px + 1) * 64 + 6) / 7;
    int ch = threadIdx.x;
    float s = 0.f;
    for (int y = ys; y < ye; ++y)
        for (int x = xs; x < xe; ++x)
            s += bf2f(q[((size_t)(b * 4096) + y * 64 + x) * 256 + ch]);
    agent[((size_t)(b * 49) + a) * 256 + ch] = s / (float)((ye - ys) * (xe - xs));
}

// ---------------------------------------------------------------------------
// K3a: pbias[h][a][pos] (bilerp + ah + aw).  grid 392, block 256.
// ---------------------------------------------------------------------------
__global__ __launch_bounds__(256) void make_pbias(
    const float* __restrict__ an, const float* __restrict__ ahb,
    const float* __restrict__ awb, float* __restrict__ pbias)
{
    int bid = blockIdx.x;               // h*49 + a
    __shared__ float bb[49], ay[64], ax[64];
    int tid = threadIdx.x;
    if (tid < 49) bb[tid] = an[(size_t)bid * 49 + tid];
    if (tid < 64) {
        ay[tid] = ahb[(size_t)bid * 64 + tid];
        ax[tid] = awb[(size_t)bid * 64 + tid];
    }
    __syncthreads();
    for (int it = 0; it < 16; ++it) {
        int pos = it * 256 + tid;
        int y = pos >> 6, x = pos & 63;
        float fy = (y + 0.5f) * (7.f / 64.f) - 0.5f; fy = fminf(fmaxf(fy, 0.f), 6.f);
        float fx = (x + 0.5f) * (7.f / 64.f) - 0.5f; fx = fminf(fmaxf(fx, 0.f), 6.f);
        int y0 = (int)fy, x0 = (int)fx;
        int y1 = min(y0 + 1, 6), x1 = min(x0 + 1, 6);
        float wy = fy - y0, wx = fx - x0;
        float val = (1.f - wy) * ((1.f - wx) * bb[y0 * 7 + x0] + wx * bb[y0 * 7 + x1])
                  + wy * ((1.f - wx) * bb[y1 * 7 + x0] + wx * bb[y1 * 7 + x1]);
        pbias[(size_t)bid * 4096 + pos] = val + ay[y] + ax[x];
    }
}

// ---------------------------------------------------------------------------
// K3b: abias[h][pos][a] (bilerp + ha + wa).  grid 392, block 256.
// ---------------------------------------------------------------------------
__global__ __launch_bounds__(256) void make_abias(
    const float* __restrict__ na, const float* __restrict__ hab,
    const float* __restrict__ wab, float* __restrict__ abias)
{
    int bid = blockIdx.x;
    int h = bid / 49, a = bid % 49;
    __shared__ float bb[49], hy[64], wx_[64];
    int tid = threadIdx.x;
    if (tid < 49) bb[tid] = na[(size_t)bid * 49 + tid];
    if (tid < 64) {
        hy[tid]  = hab[((size_t)(h * 64) + tid) * 49 + a];
        wx_[tid] = wab[((size_t)(h * 64) + tid) * 49 + a];
    }
    __syncthreads();
    for (int it = 0; it < 16; ++it) {
        int pos = it * 256 + tid;
        int y = pos >> 6, x = pos & 63;
        float fy = (y + 0.5f) * (7.f / 64.f) - 0.5f; fy = fminf(fmaxf(fy, 0.f), 6.f);
        float fx = (x + 0.5f) * (7.f / 64.f) - 0.5f; fx = fminf(fmaxf(fx, 0.f), 6.f);
        int y0 = (int)fy, x0 = (int)fx;
        int y1 = min(y0 + 1, 6), x1 = min(x0 + 1, 6);
        float wy = fy - y0, wxv = fx - x0;
        float val = (1.f - wy) * ((1.f - wxv) * bb[y0 * 7 + x0] + wxv * bb[y0 * 7 + x1])
                  + wy * ((1.f - wxv) * bb[y1 * 7 + x0] + wxv * bb[y1 * 7 + x1]);
        abias[((size_t)(h * 4096) + pos) * 49 + a] = val + hy[y] + wx_[x];
    }
}

// ---------------------------------------------------------------------------
// K4: stage-1 attention (linear-softmax split over n).  grid 1024, block 256.
// ---------------------------------------------------------------------------
__global__ __launch_bounds__(256) void stage1(
    const float* __restrict__ agent, const bf16* __restrict__ k,
    const bf16* __restrict__ v, const float* __restrict__ pbias,
    float* __restrict__ part_O, float* __restrict__ part_sum)
{
    const int bid = blockIdx.x;
    const int split = bid & 7, h = (bid >> 3) & 7, b = bid >> 6;
    const int tid = threadIdx.x;
    __shared__ float e_lds[64 * 129];   // [a][n_loc], stride 129: <=2-way conflicts

    const int n_loc = tid & 127;
    const int half  = __builtin_amdgcn_readfirstlane(tid >> 7);  // wave-uniform
    const int a0 = half * 25, na = half ? 24 : 25;
    const int wv   = __builtin_amdgcn_readfirstlane(tid >> 6);   // wave id 0..3
    const int lane = tid & 63;
    const int aL = lane < 49 ? lane : 48;

    float o[8] = {0.f, 0.f, 0.f, 0.f, 0.f, 0.f, 0.f, 0.f};
    float sacc = 0.f;

    for (int tile = 0; tile < 4; ++tile) {
        const int nbase = split * 512 + tile * 128;
        __syncthreads();                       // e_lds free from previous tile
        // ---- score phase ----
        {
            const int n_glob = nbase + n_loc;
            float kf[32];
            const bf16* kr = k + ((size_t)(b * 4096) + n_glob) * 256 + h * 32;
            load8bf(kr, kf); load8bf(kr + 8, kf + 8);
            load8bf(kr + 16, kf + 16); load8bf(kr + 24, kf + 24);
            const float* aqb = agent + ((size_t)(b * 49) + a0) * 256 + h * 32;
            const float* pbb = pbias + ((size_t)(h * 49) + a0) * 4096 + n_glob;
            for (int ai = 0; ai < na; ++ai) {
                const float* aq = aqb + (size_t)ai * 256;   // wave-uniform addr
                float dot = 0.f;
                #pragma unroll
                for (int d = 0; d < 32; ++d) dot = fmaf(aq[d], kf[d], dot);
                float s = dot * SCALE + pbb[(size_t)ai * 4096];
                e_lds[(a0 + ai) * 129 + n_loc] = __expf(s);
            }
        }
        __syncthreads();                       // e_lds ready
        // ---- PV phase ----
        {
            const uint4* vrow = reinterpret_cast<const uint4*>(
                v + ((size_t)(b * 4096) + nbase) * 256 + h * 32 + wv * 8);
            for (int nn = 0; nn < 128; ++nn) {
                float e = e_lds[aL * 129 + nn];
                uint4 pk = vrow[(size_t)nn * 32];            // wave-uniform addr
                float vf[8];
                vf[0] = __uint_as_float(pk.x << 16); vf[1] = __uint_as_float(pk.x & 0xffff0000u);
                vf[2] = __uint_as_float(pk.y << 16); vf[3] = __uint_as_float(pk.y & 0xffff0000u);
                vf[4] = __uint_as_float(pk.z << 16); vf[5] = __uint_as_float(pk.z & 0xffff0000u);
                vf[6] = __uint_as_float(pk.w << 16); vf[7] = __uint_as_float(pk.w & 0xffff0000u);
                #pragma unroll
                for (int j = 0; j < 8; ++j) o[j] = fmaf(e, vf[j], o[j]);
                sacc += e;
            }
        }
    }
    if (lane < 49) {
        float* dst = part_O + ((size_t)((b * 8 + h) * 8 + split)) * 1568 + lane * 32 + wv * 8;
        float4 w0 = make_float4(o[0], o[1], o[2], o[3]);
        float4 w1 = make_float4(o[4], o[5], o[6], o[7]);
        *reinterpret_cast<float4*>(dst)     = w0;
        *reinterpret_cast<float4*>(dst + 4) = w1;
        if (wv == 0)
            part_sum[((b * 8 + h) * 8 + split) * 49 + lane] = sacc;
    }
}

// K4b: combine split partials.  grid 128 (b*8+h), block 256.
__global__ __launch_bounds__(256) void stage1_fin(
    const float* __restrict__ part_O, const float* __restrict__ part_sum,
    float* __restrict__ agent_v)
{
    int bh = blockIdx.x;
    __shared__ float inv[49];
    int tid = threadIdx.x;
    if (tid < 49) {
        float s = 0.f;
        #pragma unroll
        for (int sp = 0; sp < 8; ++sp) s += part_sum[(bh * 8 + sp) * 49 + tid];
        inv[tid] = 1.f / s;
    }
    __syncthreads();
    for (int idx = tid; idx < 1568; idx += 256) {
        float o = 0.f;
        #pragma unroll
        for (int sp = 0; sp < 8; ++sp) o += part_O[((size_t)(bh * 8) + sp) * 1568 + idx];
        agent_v[(size_t)bh * 1568 + idx] = o * inv[idx >> 5];
    }
}

// ---------------------------------------------------------------------------
// K5: stage-2 attention (49-way softmax per query) + fused depthwise 3x3 conv.
// One thread per (b,h,pos).  grid (128, 16), block 256.
// ---------------------------------------------------------------------------
__global__ __launch_bounds__(256) void stage2(
    const bf16* __restrict__ q, const bf16* __restrict__ v,
    const float* __restrict__ agent, const float* __restrict__ agent_v,
    const float* __restrict__ abias, const float* __restrict__ wdwc,
    const float* __restrict__ bdwc, bf16* __restrict__ mid)
{
    int bh = blockIdx.x;
    int b = bh >> 3, h = bh & 7;
    int pos0 = blockIdx.y * 256;
    __shared__ float ag[49 * 32];
    __shared__ float av[49 * 32];
    __shared__ float sab[256 * 49];
    __shared__ float wd[32 * 9];
    __shared__ float bd[32];
    int tid = threadIdx.x;
    for (int i = tid; i < 1568; i += 256) {
        ag[i] = agent[((size_t)(b * 49) + (i >> 5)) * 256 + h * 32 + (i & 31)];
        av[i] = agent_v[(((size_t)(b * 8) + h) * 49) * 32 + i];
    }
    for (int i = tid; i < 256 * 49; i += 256)
        sab[i] = abias[((size_t)(h * 4096) + pos0) * 49 + i];
    if (tid < 32) {
        #pragma unroll
        for (int j = 0; j < 9; ++j) wd[tid * 9 + j] = wdwc[(h * 32 + tid) * 9 + j];
        bd[tid] = bdwc[h * 32 + tid];
    }
    __syncthreads();

    int pos = pos0 + tid;
    float qv[32];
    {
        const bf16* qr = q + ((size_t)(b * 4096) + pos) * 256 + h * 32;
        #pragma unroll
        for (int u = 0; u < 4; ++u) {
            float f[8]; load8bf(qr + u * 8, f);
            #pragma unroll
            for (int d = 0; d < 8; ++d) qv[u * 8 + d] = f[d] * SCALE;
        }
    }
    float s[49];
    float m = -1e30f;
    #pragma unroll
    for (int a = 0; a < 49; ++a) {
        float t = sab[tid * 49 + a];
        #pragma unroll
        for (int d = 0; d < 32; ++d) t += qv[d] * ag[a * 32 + d];
        s[a] = t; m = fmaxf(m, t);
    }
    float sum = 0.f;
    #pragma unroll
    for (int a = 0; a < 49; ++a) { float e = __expf(s[a] - m); s[a] = e; sum += e; }
    float inv = 1.f / sum;
    float acc[32];
    #pragma unroll
    for (int d = 0; d < 32; ++d) acc[d] = 0.f;
    #pragma unroll
    for (int a = 0; a < 49; ++a) {
        float pa = s[a] * inv;
        #pragma unroll
        for (int d = 0; d < 32; ++d) acc[d] += pa * av[a * 32 + d];
    }
    // fused depthwise 3x3 conv on v (zero pad), channels h*32..h*32+31
    int y = pos >> 6, x = pos & 63;
    #pragma unroll
    for (int dy = -1; dy <= 1; ++dy) {
        int yy = y + dy; if (yy < 0 || yy > 63) continue;
        #pragma unroll
        for (int dx = -1; dx <= 1; ++dx) {
            int xx = x + dx; if (xx < 0 || xx > 63) continue;
            const bf16* vr = v + ((size_t)(b * 4096) + yy * 64 + xx) * 256 + h * 32;
            int widx = (dy + 1) * 3 + (dx + 1);
            #pragma unroll
            for (int u = 0; u < 4; ++u) {
                float f[8]; load8bf(vr + u * 8, f);
                #pragma unroll
                for (int d = 0; d < 8; ++d) acc[u * 8 + d] += wd[(u * 8 + d) * 9 + widx] * f[d];
            }
        }
    }
    #pragma unroll
    for (int d = 0; d < 32; ++d) acc[d] += bd[d];

    bf16* dst = mid + ((size_t)(b * 4096) + pos) * 256 + h * 32;
    #pragma unroll
    for (int u = 0; u < 4; ++u) {
        ushort4 w;
        w.x = f2bf(acc[u * 8 + 0]);
        w.y = f2bf(acc[u * 8 + 1]);
        w.z = f2bf(acc[u * 8 + 2]);
        w.w = f2bf(acc[u * 8 + 3]);
        ushort4 w2;
        w2.x = f2bf(acc[u * 8 + 4]);
        w2.y = f2bf(acc[u * 8 + 5]);
        w2.z = f2bf(acc[u * 8 + 6]);
        w2.w = f2bf(acc[u * 8 + 7]);
        *reinterpret_cast<ushort4*>(dst + u * 8)     = w;
        *reinterpret_cast<ushort4*>(dst + u * 8 + 4) = w2;
    }
}

// ---------------------------------------------------------------------------
// K7: proj MFMA GEMM.  D[m=ch][n=pos] = Wp (256x256) . mid[b]^T (256x4096).
// Store transposed layout out[b][ch][pos] fp32, 64B-coalesced along pos.
// grid (2, 512), block 256.
// ---------------------------------------------------------------------------
__global__ __launch_bounds__(256) void proj_mfma(
    const bf16* __restrict__ mid, const bf16* __restrict__ Wp,
    const float* __restrict__ bp, float* __restrict__ out)
{
    __shared__ __align__(16) short As[128 * 32];
    __shared__ __align__(16) short Bs[128 * 32];
    const int m0 = blockIdx.x * 128;           // ch tile
    const int b  = blockIdx.y >> 5;
    const int n0 = (blockIdx.y & 31) * 128;    // pos tile
    const int tid = threadIdx.x;
    const int w = tid >> 6, lane = tid & 63;
    const int wm = w & 1, wn = w >> 1;
    const int quad = lane >> 4, ln = lane & 15;

    const short* Ag = (const short*)Wp + (size_t)m0 * 256;
    const short* Bg = (const short*)mid + ((size_t)(b * 4096 + n0)) * 256;
    const int ldrow = lane >> 2;
    const int ldcol = (lane & 3) * 8;

    f32x4 acc[4][4] = {};

    for (int k0 = 0; k0 < 256; k0 += 32) {
        __syncthreads();
        #pragma unroll
        for (int p = 0; p < 2; ++p) {
            int row = w * 32 + p * 16;
            gload16(Ag + (size_t)(row + ldrow) * 256 + k0 + ldcol, As + row * 32);
            gload16(Bg + (size_t)(row + ldrow) * 256 + k0 + ldcol, Bs + row * 32);
        }
        __syncthreads();
        short8 af[4], bfr[4];
        #pragma unroll
        for (int mi = 0; mi < 4; ++mi)
            af[mi] = *reinterpret_cast<const short8*>(&As[(wm * 64 + mi * 16 + ln) * 32 + quad * 8]);
        #pragma unroll
        for (int ni = 0; ni < 4; ++ni)
            bfr[ni] = *reinterpret_cast<const short8*>(&Bs[(wn * 64 + ni * 16 + ln) * 32 + quad * 8]);
        #pragma unroll
        for (int mi = 0; mi < 4; ++mi)
            #pragma unroll
            for (int ni = 0; ni < 4; ++ni)
                acc[mi][ni] = __builtin_amdgcn_mfma_f32_16x16x32_bf16(
                    af[mi], bfr[ni], acc[mi][ni], 0, 0, 0);
    }

    #pragma unroll
    for (int mi = 0; mi < 4; ++mi)
        #pragma unroll
        for (int r = 0; r < 4; ++r) {
            int ch = m0 + wm * 64 + mi * 16 + quad * 4 + r;
            float bias = bp[ch];
            float* o = out + ((size_t)(b * 256 + ch)) * 4096 + n0 + wn * 64 + ln;
            #pragma unroll
            for (int ni = 0; ni < 4; ++ni)
                o[ni * 16] = acc[mi][ni][r] + bias;
        }
}

extern "C" void kernel_launch(void* const* d_in, const int* in_sizes, int n_in,
                              void* d_out, int out_size, void* d_ws, size_t ws_size,
                              hipStream_t stream)
{
    const float* x       = (const float*)d_in[0];
    const float* Wq      = (const float*)d_in[1];
    const float* Wkv     = (const float*)d_in[2];
    const float* Wproj   = (const float*)d_in[3];
    const float* bproj   = (const float*)d_in[4];
    const float* Wdwc    = (const float*)d_in[5];
    const float* bdwc    = (const float*)d_in[6];
    const float* an_bias = (const float*)d_in[7];
    const float* na_bias = (const float*)d_in[8];
    const float* ah_bias = (const float*)d_in[9];
    const float* aw_bias = (const float*)d_in[10];
    const float* ha_bias = (const float*)d_in[11];
    const float* wa_bias = (const float*)d_in[12];
    // H=64, W=64 hard-coded (d_in[13], d_in[14])

    char* ws = (char*)d_ws;
    bf16*  q      = (bf16*)(ws + 0);
    bf16*  k      = (bf16*)(ws + 33554432);
    bf16*  v      = (bf16*)(ws + 67108864);
    // the 33.5 MB region at 100663296 is triple-used over time:
    //   1) xT (qkv input), 2) stage1 partials, 3) mid (stage2 out / proj in)
    bf16*  xT     = (bf16*)(ws + 100663296);
    float* part_O   = (float*)(ws + 100663296);
    float* part_sum = (float*)(ws + 100663296 + 6422528);
    bf16*  mid    = (bf16*)(ws + 100663296);
    float* agent  = (float*)(ws + 134217728);
    float* agentv = (float*)(ws + 135020544);
    float* pbias  = (float*)(ws + 135823360);
    float* abias  = (float*)(ws + 142245888);
    bf16*  Wqkv_bf = (bf16*)(ws + 148668416);
    bf16*  Wp_bf   = (bf16*)(ws + 149061632);
    float* out    = (float*)d_out;

    convert_w <<<dim3(1024),     256, 0, stream>>>(Wq, Wkv, Wproj, Wqkv_bf, Wp_bf);
    x_to_bf16T<<<dim3(64, 4, 16),256, 0, stream>>>(x, xT);
    qkv_mfma  <<<dim3(512, 6),   256, 0, stream>>>(xT, Wqkv_bf, q, k, v);
    pool_agent<<<dim3(784),      256, 0, stream>>>(q, agent);
    make_pbias<<<dim3(392),      256, 0, stream>>>(an_bias, ah_bias, aw_bias, pbias);
    make_abias<<<dim3(392),      256, 0, stream>>>(na_bias, ha_bias, wa_bias, abias);
    stage1    <<<dim3(1024),     256, 0, stream>>>(agent, k, v, pbias, part_O, part_sum);
    stage1_fin<<<dim3(128),      256, 0, stream>>>(part_O, part_sum, agentv);
    stage2    <<<dim3(128, 16),  256, 0, stream>>>(q, v, agent, agentv, abias, Wdwc, bdwc, mid);
    proj_mfma <<<dim3(2, 512),   256, 0, stream>>>(mid, Wp_bf, bproj, out);
}

// Round 5
// 442.610 us; speedup vs baseline: 3.7605x; 1.2434x over previous
//
#include <hip/hip_runtime.h>
#include <hip/hip_bf16.h>
#include <stdint.h>

using bf16 = __hip_bfloat16;

#define SCALE 0.17677669529663687f   // 32^-0.5

typedef short short8 __attribute__((ext_vector_type(8)));
typedef float f32x4 __attribute__((ext_vector_type(4)));

__device__ __forceinline__ float bf2f(bf16 v) { return __bfloat162float(v); }

__device__ __forceinline__ unsigned short f2bf(float f) {
    unsigned int u = __float_as_uint(f);
    unsigned int r = u + 0x7fffu + ((u >> 16) & 1u);   // RNE; inputs never NaN/Inf
    return (unsigned short)(r >> 16);
}

// load 8 consecutive bf16 (16B-aligned) -> 8 floats
__device__ __forceinline__ void load8bf(const bf16* p, float* f) {
    uint4 u = *reinterpret_cast<const uint4*>(p);
    f[0] = __uint_as_float(u.x << 16); f[1] = __uint_as_float(u.x & 0xffff0000u);
    f[2] = __uint_as_float(u.y << 16); f[3] = __uint_as_float(u.y & 0xffff0000u);
    f[4] = __uint_as_float(u.z << 16); f[5] = __uint_as_float(u.z & 0xffff0000u);
    f[6] = __uint_as_float(u.w << 16); f[7] = __uint_as_float(u.w & 0xffff0000u);
}

__device__ __forceinline__ void gload16(const void* g, void* l) {
    __builtin_amdgcn_global_load_lds(
        (const __attribute__((address_space(1))) void*)g,
        (__attribute__((address_space(3))) void*)l, 16, 0, 0);
}

// ---------------------------------------------------------------------------
// K0a: convert weights to bf16.  grid 1024, block 256.
// ---------------------------------------------------------------------------
__global__ __launch_bounds__(256) void convert_w(
    const float* __restrict__ Wq, const float* __restrict__ Wkv,
    const float* __restrict__ Wp,
    bf16* __restrict__ Wqkv_bf, bf16* __restrict__ Wp_bf)
{
    int row = blockIdx.x, tid = threadIdx.x;
    const float* src; bf16* dst;
    if (row < 768) {
        src = (row < 256) ? Wq + (size_t)row * 256 : Wkv + (size_t)(row - 256) * 256;
        dst = Wqkv_bf + (size_t)row * 256;
    } else {
        src = Wp + (size_t)(row - 768) * 256;
        dst = Wp_bf + (size_t)(row - 768) * 256;
    }
    *reinterpret_cast<unsigned short*>(dst + tid) = f2bf(src[tid]);
}

// ---------------------------------------------------------------------------
// K0b: xT[b][pos][c] = bf16(x[b][c][pos]).  64x64 LDS tile transpose.
// grid (64, 4, 16), block 256.
// ---------------------------------------------------------------------------
__global__ __launch_bounds__(256) void x_to_bf16T(
    const float* __restrict__ x, bf16* __restrict__ xT)
{
    __shared__ float t[64][65];
    const int b = blockIdx.z, pos0 = blockIdx.x * 64, c0 = blockIdx.y * 64;
    const int tid = threadIdx.x;
    const int cc = tid >> 6, p = tid & 63;
    #pragma unroll
    for (int i = 0; i < 16; ++i)
        t[cc + 4 * i][p] = x[((size_t)(b * 256 + c0 + cc + 4 * i)) * 4096 + pos0 + p];
    __syncthreads();
    const int pl = tid >> 2, qd = tid & 3;
    unsigned short tmp[16];
    #pragma unroll
    for (int j = 0; j < 16; ++j) tmp[j] = f2bf(t[qd * 16 + j][pl]);
    uint4* dst = reinterpret_cast<uint4*>(xT + ((size_t)(b * 4096 + pos0 + pl)) * 256 + c0 + qd * 16);
    dst[0] = reinterpret_cast<const uint4*>(tmp)[0];
    dst[1] = reinterpret_cast<const uint4*>(tmp)[1];
}

// ---------------------------------------------------------------------------
// K1: qkv MFMA GEMM.  D[m=pos][n=ch] = xT[b] (4096x256) . Wqkv^T (256x768).
// 128x128 tile, BK=32, 4 waves x (4x4 16x16x32 mfma).  grid (512, 6), block 256.
// ---------------------------------------------------------------------------
__global__ __launch_bounds__(256) void qkv_mfma(
    const bf16* __restrict__ xT, const bf16* __restrict__ Wqkv,
    bf16* __restrict__ q, bf16* __restrict__ k, bf16* __restrict__ v)
{
    __shared__ __align__(16) short As[128 * 32];
    __shared__ __align__(16) short Bs[128 * 32];
    const int b = blockIdx.x >> 5;
    const int m0 = (blockIdx.x & 31) * 128;
    const int j0 = blockIdx.y * 128;
    const int tid = threadIdx.x;
    const int w = tid >> 6, lane = tid & 63;
    const int wm = w & 1, wn = w >> 1;
    const int quad = lane >> 4, ln = lane & 15;

    const short* Ag = (const short*)xT + ((size_t)(b * 4096 + m0)) * 256;
    const short* Bg = (const short*)Wqkv + (size_t)j0 * 256;
    const int ldrow = lane >> 2;            // 0..15
    const int ldcol = (lane & 3) * 8;       // element offset within row

    f32x4 acc[4][4] = {};

    for (int k0 = 0; k0 < 256; k0 += 32) {
        __syncthreads();
        #pragma unroll
        for (int p = 0; p < 2; ++p) {
            int row = w * 32 + p * 16;
            gload16(Ag + (size_t)(row + ldrow) * 256 + k0 + ldcol, As + row * 32);
            gload16(Bg + (size_t)(row + ldrow) * 256 + k0 + ldcol, Bs + row * 32);
        }
        __syncthreads();
        short8 af[4], bfr[4];
        #pragma unroll
        for (int mi = 0; mi < 4; ++mi)
            af[mi] = *reinterpret_cast<const short8*>(&As[(wm * 64 + mi * 16 + ln) * 32 + quad * 8]);
        #pragma unroll
        for (int ni = 0; ni < 4; ++ni)
            bfr[ni] = *reinterpret_cast<const short8*>(&Bs[(wn * 64 + ni * 16 + ln) * 32 + quad * 8]);
        #pragma unroll
        for (int mi = 0; mi < 4; ++mi)
            #pragma unroll
            for (int ni = 0; ni < 4; ++ni)
                acc[mi][ni] = __builtin_amdgcn_mfma_f32_16x16x32_bf16(
                    af[mi], bfr[ni], acc[mi][ni], 0, 0, 0);
    }

    bf16* dst; int cb;
    if (j0 < 256)      { dst = q; cb = j0; }
    else if (j0 < 512) { dst = k; cb = j0 - 256; }
    else               { dst = v; cb = j0 - 512; }
    #pragma unroll
    for (int mi = 0; mi < 4; ++mi)
        #pragma unroll
        for (int r = 0; r < 4; ++r) {
            int pos = m0 + wm * 64 + mi * 16 + quad * 4 + r;
            unsigned short* o = reinterpret_cast<unsigned short*>(
                dst + ((size_t)(b * 4096 + pos)) * 256 + cb + wn * 64 + ln);
            #pragma unroll
            for (int ni = 0; ni < 4; ++ni)
                o[ni * 16] = f2bf(acc[mi][ni][r]);
        }
}

// ---------------------------------------------------------------------------
// K2: agent tokens = adaptive avg pool 64x64 -> 7x7 of q.  grid 784, block 256.
// ---------------------------------------------------------------------------
__global__ __launch_bounds__(256) void pool_agent(
    const bf16* __restrict__ q, float* __restrict__ agent)
{
    int bid = blockIdx.x;
    int b = bid / 49, a = bid % 49;
    int py = a / 7, px = a % 7;
    int ys = (py * 64) / 7, ye = ((py + 1) * 64 + 6) / 7;
    int xs = (px * 64) / 7, xe = ((px + 1) * 64 + 6) / 7;
    int ch = threadIdx.x;
    float s = 0.f;
    for (int y = ys; y < ye; ++y)
        for (int x = xs; x < xe; ++x)
            s += bf2f(q[((size_t)(b * 4096) + y * 64 + x) * 256 + ch]);
    agent[((size_t)(b * 49) + a) * 256 + ch] = s / (float)((ye - ys) * (xe - xs));
}

// ---------------------------------------------------------------------------
// K3a: pbias[h][a][pos] (bilerp + ah + aw).  grid 392, block 256.
// ---------------------------------------------------------------------------
__global__ __launch_bounds__(256) void make_pbias(
    const float* __restrict__ an, const float* __restrict__ ahb,
    const float* __restrict__ awb, float* __restrict__ pbias)
{
    int bid = blockIdx.x;               // h*49 + a
    __shared__ float bb[49], ay[64], ax[64];
    int tid = threadIdx.x;
    if (tid < 49) bb[tid] = an[(size_t)bid * 49 + tid];
    if (tid < 64) {
        ay[tid] = ahb[(size_t)bid * 64 + tid];
        ax[tid] = awb[(size_t)bid * 64 + tid];
    }
    __syncthreads();
    for (int it = 0; it < 16; ++it) {
        int pos = it * 256 + tid;
        int y = pos >> 6, x = pos & 63;
        float fy = (y + 0.5f) * (7.f / 64.f) - 0.5f; fy = fminf(fmaxf(fy, 0.f), 6.f);
        float fx = (x + 0.5f) * (7.f / 64.f) - 0.5f; fx = fminf(fmaxf(fx, 0.f), 6.f);
        int y0 = (int)fy, x0 = (int)fx;
        int y1 = min(y0 + 1, 6), x1 = min(x0 + 1, 6);
        float wy = fy - y0, wx = fx - x0;
        float val = (1.f - wy) * ((1.f - wx) * bb[y0 * 7 + x0] + wx * bb[y0 * 7 + x1])
                  + wy * ((1.f - wx) * bb[y1 * 7 + x0] + wx * bb[y1 * 7 + x1]);
        pbias[(size_t)bid * 4096 + pos] = val + ay[y] + ax[x];
    }
}

// ---------------------------------------------------------------------------
// K3b: abiasT[h][a][pos] (bilerp + ha + wa), TRANSPOSED layout so stage2 reads
// are pos-coalesced.  grid 392, block 256.
// ---------------------------------------------------------------------------
__global__ __launch_bounds__(256) void make_abias(
    const float* __restrict__ na, const float* __restrict__ hab,
    const float* __restrict__ wab, float* __restrict__ abiasT)
{
    int bid = blockIdx.x;               // h*49 + a
    int h = bid / 49, a = bid % 49;
    __shared__ float bb[49], hy[64], wx_[64];
    int tid = threadIdx.x;
    if (tid < 49) bb[tid] = na[(size_t)bid * 49 + tid];
    if (tid < 64) {
        hy[tid]  = hab[((size_t)(h * 64) + tid) * 49 + a];
        wx_[tid] = wab[((size_t)(h * 64) + tid) * 49 + a];
    }
    __syncthreads();
    for (int it = 0; it < 16; ++it) {
        int pos = it * 256 + tid;
        int y = pos >> 6, x = pos & 63;
        float fy = (y + 0.5f) * (7.f / 64.f) - 0.5f; fy = fminf(fmaxf(fy, 0.f), 6.f);
        float fx = (x + 0.5f) * (7.f / 64.f) - 0.5f; fx = fminf(fmaxf(fx, 0.f), 6.f);
        int y0 = (int)fy, x0 = (int)fx;
        int y1 = min(y0 + 1, 6), x1 = min(x0 + 1, 6);
        float wy = fy - y0, wxv = fx - x0;
        float val = (1.f - wy) * ((1.f - wxv) * bb[y0 * 7 + x0] + wxv * bb[y0 * 7 + x1])
                  + wy * ((1.f - wxv) * bb[y1 * 7 + x0] + wxv * bb[y1 * 7 + x1]);
        abiasT[(size_t)bid * 4096 + pos] = val + hy[y] + wx_[x];
    }
}

// ---------------------------------------------------------------------------
// K4: stage-1 attention (linear-softmax split over n).  grid 1024, block 256.
// ---------------------------------------------------------------------------
__global__ __launch_bounds__(256) void stage1(
    const float* __restrict__ agent, const bf16* __restrict__ k,
    const bf16* __restrict__ v, const float* __restrict__ pbias,
    float* __restrict__ part_O, float* __restrict__ part_sum)
{
    const int bid = blockIdx.x;
    const int split = bid & 7, h = (bid >> 3) & 7, b = bid >> 6;
    const int tid = threadIdx.x;
    __shared__ float e_lds[64 * 129];   // [a][n_loc], stride 129: <=2-way conflicts

    const int n_loc = tid & 127;
    const int half  = __builtin_amdgcn_readfirstlane(tid >> 7);  // wave-uniform
    const int a0 = half * 25, na = half ? 24 : 25;
    const int wv   = __builtin_amdgcn_readfirstlane(tid >> 6);   // wave id 0..3
    const int lane = tid & 63;
    const int aL = lane < 49 ? lane : 48;

    float o[8] = {0.f, 0.f, 0.f, 0.f, 0.f, 0.f, 0.f, 0.f};
    float sacc = 0.f;

    for (int tile = 0; tile < 4; ++tile) {
        const int nbase = split * 512 + tile * 128;
        __syncthreads();                       // e_lds free from previous tile
        // ---- score phase ----
        {
            const int n_glob = nbase + n_loc;
            float kf[32];
            const bf16* kr = k + ((size_t)(b * 4096) + n_glob) * 256 + h * 32;
            load8bf(kr, kf); load8bf(kr + 8, kf + 8);
            load8bf(kr + 16, kf + 16); load8bf(kr + 24, kf + 24);
            const float* aqb = agent + ((size_t)(b * 49) + a0) * 256 + h * 32;
            const float* pbb = pbias + ((size_t)(h * 49) + a0) * 4096 + n_glob;
            for (int ai = 0; ai < na; ++ai) {
                const float* aq = aqb + (size_t)ai * 256;   // wave-uniform addr
                float dot = 0.f;
                #pragma unroll
                for (int d = 0; d < 32; ++d) dot = fmaf(aq[d], kf[d], dot);
                float s = dot * SCALE + pbb[(size_t)ai * 4096];
                e_lds[(a0 + ai) * 129 + n_loc] = __expf(s);
            }
        }
        __syncthreads();                       // e_lds ready
        // ---- PV phase ----
        {
            const uint4* vrow = reinterpret_cast<const uint4*>(
                v + ((size_t)(b * 4096) + nbase) * 256 + h * 32 + wv * 8);
            for (int nn = 0; nn < 128; ++nn) {
                float e = e_lds[aL * 129 + nn];
                uint4 pk = vrow[(size_t)nn * 32];            // wave-uniform addr
                float vf[8];
                vf[0] = __uint_as_float(pk.x << 16); vf[1] = __uint_as_float(pk.x & 0xffff0000u);
                vf[2] = __uint_as_float(pk.y << 16); vf[3] = __uint_as_float(pk.y & 0xffff0000u);
                vf[4] = __uint_as_float(pk.z << 16); vf[5] = __uint_as_float(pk.z & 0xffff0000u);
                vf[6] = __uint_as_float(pk.w << 16); vf[7] = __uint_as_float(pk.w & 0xffff0000u);
                #pragma unroll
                for (int j = 0; j < 8; ++j) o[j] = fmaf(e, vf[j], o[j]);
                sacc += e;
            }
        }
    }
    if (lane < 49) {
        float* dst = part_O + ((size_t)((b * 8 + h) * 8 + split)) * 1568 + lane * 32 + wv * 8;
        float4 w0 = make_float4(o[0], o[1], o[2], o[3]);
        float4 w1 = make_float4(o[4], o[5], o[6], o[7]);
        *reinterpret_cast<float4*>(dst)     = w0;
        *reinterpret_cast<float4*>(dst + 4) = w1;
        if (wv == 0)
            part_sum[((b * 8 + h) * 8 + split) * 49 + lane] = sacc;
    }
}

// K4b: combine split partials.  grid 128 (b*8+h), block 256.
__global__ __launch_bounds__(256) void stage1_fin(
    const float* __restrict__ part_O, const float* __restrict__ part_sum,
    float* __restrict__ agent_v)
{
    int bh = blockIdx.x;
    __shared__ float inv[49];
    int tid = threadIdx.x;
    if (tid < 49) {
        float s = 0.f;
        #pragma unroll
        for (int sp = 0; sp < 8; ++sp) s += part_sum[(bh * 8 + sp) * 49 + tid];
        inv[tid] = 1.f / s;
    }
    __syncthreads();
    for (int idx = tid; idx < 1568; idx += 256) {
        float o = 0.f;
        #pragma unroll
        for (int sp = 0; sp < 8; ++sp) o += part_O[((size_t)(bh * 8) + sp) * 1568 + idx];
        agent_v[(size_t)bh * 1568 + idx] = o * inv[idx >> 5];
    }
}

// ---------------------------------------------------------------------------
// K5: stage-2 attention, zero-LDS version.  Linear softmax (|s|<1) streamed
// over a; ag/av/wd/bd via wave-uniform scalar loads; abiasT pos-coalesced.
// One thread per (b,h,pos).  grid (128, 16), block 256.
// ---------------------------------------------------------------------------
__global__ __launch_bounds__(256) void stage2(
    const bf16* __restrict__ q, const bf16* __restrict__ v,
    const float* __restrict__ agent, const float* __restrict__ agent_v,
    const float* __restrict__ abiasT, const float* __restrict__ wdwc,
    const float* __restrict__ bdwc, bf16* __restrict__ mid)
{
    const int bh = blockIdx.x;
    const int b = bh >> 3, h = bh & 7;
    const int pos = blockIdx.y * 256 + threadIdx.x;

    // wave-uniform bases -> scalar loads
    const float* agb = agent + ((size_t)(b * 49)) * 256 + h * 32;
    const float* avb = agent_v + (size_t)bh * 1568;
    const float* abb = abiasT + (size_t)(h * 49) * 4096 + pos;
    const float* wdb = wdwc + (size_t)(h * 32) * 9;
    const float* bdb = bdwc + h * 32;

    float qv[32];
    {
        const bf16* qr = q + ((size_t)(b * 4096) + pos) * 256 + h * 32;
        #pragma unroll
        for (int u = 0; u < 4; ++u) {
            float f[8]; load8bf(qr + u * 8, f);
            #pragma unroll
            for (int d = 0; d < 8; ++d) qv[u * 8 + d] = f[d] * SCALE;
        }
    }

    float sum = 0.f;
    float acc[32];
    #pragma unroll
    for (int d = 0; d < 32; ++d) acc[d] = 0.f;

    for (int a = 0; a < 49; ++a) {
        const float* ag = agb + (size_t)a * 256;   // wave-uniform
        const float* av = avb + a * 32;            // wave-uniform
        float t = abb[(size_t)a * 4096];           // coalesced vector load
        #pragma unroll
        for (int d = 0; d < 32; ++d) t = fmaf(qv[d], ag[d], t);
        float e = __expf(t);
        sum += e;
        #pragma unroll
        for (int d = 0; d < 32; ++d) acc[d] = fmaf(e, av[d], acc[d]);
    }
    float inv = 1.f / sum;
    #pragma unroll
    for (int d = 0; d < 32; ++d) acc[d] *= inv;

    // fused depthwise 3x3 conv on v (zero pad), channels h*32..h*32+31
    int y = pos >> 6, x = pos & 63;
    #pragma unroll
    for (int dy = -1; dy <= 1; ++dy) {
        int yy = y + dy; if (yy < 0 || yy > 63) continue;
        #pragma unroll
        for (int dx = -1; dx <= 1; ++dx) {
            int xx = x + dx; if (xx < 0 || xx > 63) continue;
            const bf16* vr = v + ((size_t)(b * 4096) + yy * 64 + xx) * 256 + h * 32;
            int widx = (dy + 1) * 3 + (dx + 1);
            #pragma unroll
            for (int u = 0; u < 4; ++u) {
                float f[8]; load8bf(vr + u * 8, f);
                #pragma unroll
                for (int d = 0; d < 8; ++d)
                    acc[u * 8 + d] = fmaf(wdb[(u * 8 + d) * 9 + widx], f[d], acc[u * 8 + d]);
            }
        }
    }
    #pragma unroll
    for (int d = 0; d < 32; ++d) acc[d] += bdb[d];

    bf16* dst = mid + ((size_t)(b * 4096) + pos) * 256 + h * 32;
    #pragma unroll
    for (int u = 0; u < 4; ++u) {
        ushort4 w;
        w.x = f2bf(acc[u * 8 + 0]);
        w.y = f2bf(acc[u * 8 + 1]);
        w.z = f2bf(acc[u * 8 + 2]);
        w.w = f2bf(acc[u * 8 + 3]);
        ushort4 w2;
        w2.x = f2bf(acc[u * 8 + 4]);
        w2.y = f2bf(acc[u * 8 + 5]);
        w2.z = f2bf(acc[u * 8 + 6]);
        w2.w = f2bf(acc[u * 8 + 7]);
        *reinterpret_cast<ushort4*>(dst + u * 8)     = w;
        *reinterpret_cast<ushort4*>(dst + u * 8 + 4) = w2;
    }
}

// ---------------------------------------------------------------------------
// K7: proj MFMA GEMM.  D[m=ch][n=pos] = Wp (256x256) . mid[b]^T (256x4096).
// grid (2, 512), block 256.
// ---------------------------------------------------------------------------
__global__ __launch_bounds__(256) void proj_mfma(
    const bf16* __restrict__ mid, const bf16* __restrict__ Wp,
    const float* __restrict__ bp, float* __restrict__ out)
{
    __shared__ __align__(16) short As[128 * 32];
    __shared__ __align__(16) short Bs[128 * 32];
    const int m0 = blockIdx.x * 128;           // ch tile
    const int b  = blockIdx.y >> 5;
    const int n0 = (blockIdx.y & 31) * 128;    // pos tile
    const int tid = threadIdx.x;
    const int w = tid >> 6, lane = tid & 63;
    const int wm = w & 1, wn = w >> 1;
    const int quad = lane >> 4, ln = lane & 15;

    const short* Ag = (const short*)Wp + (size_t)m0 * 256;
    const short* Bg = (const short*)mid + ((size_t)(b * 4096 + n0)) * 256;
    const int ldrow = lane >> 2;
    const int ldcol = (lane & 3) * 8;

    f32x4 acc[4][4] = {};

    for (int k0 = 0; k0 < 256; k0 += 32) {
        __syncthreads();
        #pragma unroll
        for (int p = 0; p < 2; ++p) {
            int row = w * 32 + p * 16;
            gload16(Ag + (size_t)(row + ldrow) * 256 + k0 + ldcol, As + row * 32);
            gload16(Bg + (size_t)(row + ldrow) * 256 + k0 + ldcol, Bs + row * 32);
        }
        __syncthreads();
        short8 af[4], bfr[4];
        #pragma unroll
        for (int mi = 0; mi < 4; ++mi)
            af[mi] = *reinterpret_cast<const short8*>(&As[(wm * 64 + mi * 16 + ln) * 32 + quad * 8]);
        #pragma unroll
        for (int ni = 0; ni < 4; ++ni)
            bfr[ni] = *reinterpret_cast<const short8*>(&Bs[(wn * 64 + ni * 16 + ln) * 32 + quad * 8]);
        #pragma unroll
        for (int mi = 0; mi < 4; ++mi)
            #pragma unroll
            for (int ni = 0; ni < 4; ++ni)
                acc[mi][ni] = __builtin_amdgcn_mfma_f32_16x16x32_bf16(
                    af[mi], bfr[ni], acc[mi][ni], 0, 0, 0);
    }

    #pragma unroll
    for (int mi = 0; mi < 4; ++mi)
        #pragma unroll
        for (int r = 0; r < 4; ++r) {
            int ch = m0 + wm * 64 + mi * 16 + quad * 4 + r;
            float bias = bp[ch];
            float* o = out + ((size_t)(b * 256 + ch)) * 4096 + n0 + wn * 64 + ln;
            #pragma unroll
            for (int ni = 0; ni < 4; ++ni)
                o[ni * 16] = acc[mi][ni][r] + bias;
        }
}

extern "C" void kernel_launch(void* const* d_in, const int* in_sizes, int n_in,
                              void* d_out, int out_size, void* d_ws, size_t ws_size,
                              hipStream_t stream)
{
    const float* x       = (const float*)d_in[0];
    const float* Wq      = (const float*)d_in[1];
    const float* Wkv     = (const float*)d_in[2];
    const float* Wproj   = (const float*)d_in[3];
    const float* bproj   = (const float*)d_in[4];
    const float* Wdwc    = (const float*)d_in[5];
    const float* bdwc    = (const float*)d_in[6];
    const float* an_bias = (const float*)d_in[7];
    const float* na_bias = (const float*)d_in[8];
    const float* ah_bias = (const float*)d_in[9];
    const float* aw_bias = (const float*)d_in[10];
    const float* ha_bias = (const float*)d_in[11];
    const float* wa_bias = (const float*)d_in[12];
    // H=64, W=64 hard-coded (d_in[13], d_in[14])

    char* ws = (char*)d_ws;
    bf16*  q      = (bf16*)(ws + 0);
    bf16*  k      = (bf16*)(ws + 33554432);
    bf16*  v      = (bf16*)(ws + 67108864);
    // the 33.5 MB region at 100663296 is triple-used over time:
    //   1) xT (qkv input), 2) stage1 partials, 3) mid (stage2 out / proj in)
    bf16*  xT     = (bf16*)(ws + 100663296);
    float* part_O   = (float*)(ws + 100663296);
    float* part_sum = (float*)(ws + 100663296 + 6422528);
    bf16*  mid    = (bf16*)(ws + 100663296);
    float* agent  = (float*)(ws + 134217728);
    float* agentv = (float*)(ws + 135020544);
    float* pbias  = (float*)(ws + 135823360);
    float* abiasT = (float*)(ws + 142245888);
    bf16*  Wqkv_bf = (bf16*)(ws + 148668416);
    bf16*  Wp_bf   = (bf16*)(ws + 149061632);
    float* out    = (float*)d_out;

    convert_w <<<dim3(1024),     256, 0, stream>>>(Wq, Wkv, Wproj, Wqkv_bf, Wp_bf);
    x_to_bf16T<<<dim3(64, 4, 16),256, 0, stream>>>(x, xT);
    qkv_mfma  <<<dim3(512, 6),   256, 0, stream>>>(xT, Wqkv_bf, q, k, v);
    pool_agent<<<dim3(784),      256, 0, stream>>>(q, agent);
    make_pbias<<<dim3(392),      256, 0, stream>>>(an_bias, ah_bias, aw_bias, pbias);
    make_abias<<<dim3(392),      256, 0, stream>>>(na_bias, ha_bias, wa_bias, abiasT);
    stage1    <<<dim3(1024),     256, 0, stream>>>(agent, k, v, pbias, part_O, part_sum);
    stage1_fin<<<dim3(128),      256, 0, stream>>>(part_O, part_sum, agentv);
    stage2    <<<dim3(128, 16),  256, 0, stream>>>(q, v, agent, agentv, abiasT, Wdwc, bdwc, mid);
    proj_mfma <<<dim3(2, 512),   256, 0, stream>>>(mid, Wp_bf, bproj, out);
}

// Round 6
// 391.279 us; speedup vs baseline: 4.2539x; 1.1312x over previous
//
#include <hip/hip_runtime.h>
#include <hip/hip_bf16.h>
#include <stdint.h>

using bf16 = __hip_bfloat16;

#define SCALE 0.17677669529663687f   // 32^-0.5

typedef short short8 __attribute__((ext_vector_type(8)));
typedef float f32x4 __attribute__((ext_vector_type(4)));

__device__ __forceinline__ float bf2f(bf16 v) { return __bfloat162float(v); }

__device__ __forceinline__ unsigned short f2bf(float f) {
    unsigned int u = __float_as_uint(f);
    unsigned int r = u + 0x7fffu + ((u >> 16) & 1u);   // RNE; inputs never NaN/Inf
    return (unsigned short)(r >> 16);
}

// load 8 consecutive bf16 (16B-aligned) -> 8 floats
__device__ __forceinline__ void load8bf(const bf16* p, float* f) {
    uint4 u = *reinterpret_cast<const uint4*>(p);
    f[0] = __uint_as_float(u.x << 16); f[1] = __uint_as_float(u.x & 0xffff0000u);
    f[2] = __uint_as_float(u.y << 16); f[3] = __uint_as_float(u.y & 0xffff0000u);
    f[4] = __uint_as_float(u.z << 16); f[5] = __uint_as_float(u.z & 0xffff0000u);
    f[6] = __uint_as_float(u.w << 16); f[7] = __uint_as_float(u.w & 0xffff0000u);
}

__device__ __forceinline__ void gload16(const void* g, void* l) {
    __builtin_amdgcn_global_load_lds(
        (const __attribute__((address_space(1))) void*)g,
        (__attribute__((address_space(3))) void*)l, 16, 0, 0);
}

// ---------------------------------------------------------------------------
// K0a: convert weights to bf16.  grid 1024, block 256.
// ---------------------------------------------------------------------------
__global__ __launch_bounds__(256) void convert_w(
    const float* __restrict__ Wq, const float* __restrict__ Wkv,
    const float* __restrict__ Wp,
    bf16* __restrict__ Wqkv_bf, bf16* __restrict__ Wp_bf)
{
    int row = blockIdx.x, tid = threadIdx.x;
    const float* src; bf16* dst;
    if (row < 768) {
        src = (row < 256) ? Wq + (size_t)row * 256 : Wkv + (size_t)(row - 256) * 256;
        dst = Wqkv_bf + (size_t)row * 256;
    } else {
        src = Wp + (size_t)(row - 768) * 256;
        dst = Wp_bf + (size_t)(row - 768) * 256;
    }
    *reinterpret_cast<unsigned short*>(dst + tid) = f2bf(src[tid]);
}

// ---------------------------------------------------------------------------
// K0b: xT[b][pos][c] = bf16(x[b][c][pos]).  64x64 LDS tile transpose.
// grid (64, 4, 16), block 256.
// ---------------------------------------------------------------------------
__global__ __launch_bounds__(256) void x_to_bf16T(
    const float* __restrict__ x, bf16* __restrict__ xT)
{
    __shared__ float t[64][65];
    const int b = blockIdx.z, pos0 = blockIdx.x * 64, c0 = blockIdx.y * 64;
    const int tid = threadIdx.x;
    const int cc = tid >> 6, p = tid & 63;
    #pragma unroll
    for (int i = 0; i < 16; ++i)
        t[cc + 4 * i][p] = x[((size_t)(b * 256 + c0 + cc + 4 * i)) * 4096 + pos0 + p];
    __syncthreads();
    const int pl = tid >> 2, qd = tid & 3;
    unsigned short tmp[16];
    #pragma unroll
    for (int j = 0; j < 16; ++j) tmp[j] = f2bf(t[qd * 16 + j][pl]);
    uint4* dst = reinterpret_cast<uint4*>(xT + ((size_t)(b * 4096 + pos0 + pl)) * 256 + c0 + qd * 16);
    dst[0] = reinterpret_cast<const uint4*>(tmp)[0];
    dst[1] = reinterpret_cast<const uint4*>(tmp)[1];
}

// ---------------------------------------------------------------------------
// K1: qkv MFMA GEMM.  D[m=pos][n=ch] = xT[b] (4096x256) . Wqkv^T (256x768).
// 128x128 tile, BK=32, 4 waves x (4x4 16x16x32 mfma).  grid (512, 6), block 256.
// ---------------------------------------------------------------------------
__global__ __launch_bounds__(256) void qkv_mfma(
    const bf16* __restrict__ xT, const bf16* __restrict__ Wqkv,
    bf16* __restrict__ q, bf16* __restrict__ k, bf16* __restrict__ v)
{
    __shared__ __align__(16) short As[128 * 32];
    __shared__ __align__(16) short Bs[128 * 32];
    const int b = blockIdx.x >> 5;
    const int m0 = (blockIdx.x & 31) * 128;
    const int j0 = blockIdx.y * 128;
    const int tid = threadIdx.x;
    const int w = tid >> 6, lane = tid & 63;
    const int wm = w & 1, wn = w >> 1;
    const int quad = lane >> 4, ln = lane & 15;

    const short* Ag = (const short*)xT + ((size_t)(b * 4096 + m0)) * 256;
    const short* Bg = (const short*)Wqkv + (size_t)j0 * 256;
    const int ldrow = lane >> 2;            // 0..15
    const int ldcol = (lane & 3) * 8;       // element offset within row

    f32x4 acc[4][4] = {};

    for (int k0 = 0; k0 < 256; k0 += 32) {
        __syncthreads();
        #pragma unroll
        for (int p = 0; p < 2; ++p) {
            int row = w * 32 + p * 16;
            gload16(Ag + (size_t)(row + ldrow) * 256 + k0 + ldcol, As + row * 32);
            gload16(Bg + (size_t)(row + ldrow) * 256 + k0 + ldcol, Bs + row * 32);
        }
        __syncthreads();
        short8 af[4], bfr[4];
        #pragma unroll
        for (int mi = 0; mi < 4; ++mi)
            af[mi] = *reinterpret_cast<const short8*>(&As[(wm * 64 + mi * 16 + ln) * 32 + quad * 8]);
        #pragma unroll
        for (int ni = 0; ni < 4; ++ni)
            bfr[ni] = *reinterpret_cast<const short8*>(&Bs[(wn * 64 + ni * 16 + ln) * 32 + quad * 8]);
        #pragma unroll
        for (int mi = 0; mi < 4; ++mi)
            #pragma unroll
            for (int ni = 0; ni < 4; ++ni)
                acc[mi][ni] = __builtin_amdgcn_mfma_f32_16x16x32_bf16(
                    af[mi], bfr[ni], acc[mi][ni], 0, 0, 0);
    }

    bf16* dst; int cb;
    if (j0 < 256)      { dst = q; cb = j0; }
    else if (j0 < 512) { dst = k; cb = j0 - 256; }
    else               { dst = v; cb = j0 - 512; }
    #pragma unroll
    for (int mi = 0; mi < 4; ++mi)
        #pragma unroll
        for (int r = 0; r < 4; ++r) {
            int pos = m0 + wm * 64 + mi * 16 + quad * 4 + r;
            unsigned short* o = reinterpret_cast<unsigned short*>(
                dst + ((size_t)(b * 4096 + pos)) * 256 + cb + wn * 64 + ln);
            #pragma unroll
            for (int ni = 0; ni < 4; ++ni)
                o[ni * 16] = f2bf(acc[mi][ni][r]);
        }
}

// ---------------------------------------------------------------------------
// K2: agent tokens = adaptive avg pool 64x64 -> 7x7 of q.  grid 784, block 256.
// ---------------------------------------------------------------------------
__global__ __launch_bounds__(256) void pool_agent(
    const bf16* __restrict__ q, float* __restrict__ agent)
{
    int bid = blockIdx.x;
    int b = bid / 49, a = bid % 49;
    int py = a / 7, px = a % 7;
    int ys = (py * 64) / 7, ye = ((py + 1) * 64 + 6) / 7;
    int xs = (px * 64) / 7, xe = ((px + 1) * 64 + 6) / 7;
    int ch = threadIdx.x;
    float s = 0.f;
    for (int y = ys; y < ye; ++y)
        for (int x = xs; x < xe; ++x)
            s += bf2f(q[((size_t)(b * 4096) + y * 64 + x) * 256 + ch]);
    agent[((size_t)(b * 49) + a) * 256 + ch] = s / (float)((ye - ys) * (xe - xs));
}

// ---------------------------------------------------------------------------
// K3a: pbias[h][a][pos] (bilerp + ah + aw).  grid 392, block 256.
// ---------------------------------------------------------------------------
__global__ __launch_bounds__(256) void make_pbias(
    const float* __restrict__ an, const float* __restrict__ ahb,
    const float* __restrict__ awb, float* __restrict__ pbias)
{
    int bid = blockIdx.x;               // h*49 + a
    __shared__ float bb[49], ay[64], ax[64];
    int tid = threadIdx.x;
    if (tid < 49) bb[tid] = an[(size_t)bid * 49 + tid];
    if (tid < 64) {
        ay[tid] = ahb[(size_t)bid * 64 + tid];
        ax[tid] = awb[(size_t)bid * 64 + tid];
    }
    __syncthreads();
    for (int it = 0; it < 16; ++it) {
        int pos = it * 256 + tid;
        int y = pos >> 6, x = pos & 63;
        float fy = (y + 0.5f) * (7.f / 64.f) - 0.5f; fy = fminf(fmaxf(fy, 0.f), 6.f);
        float fx = (x + 0.5f) * (7.f / 64.f) - 0.5f; fx = fminf(fmaxf(fx, 0.f), 6.f);
        int y0 = (int)fy, x0 = (int)fx;
        int y1 = min(y0 + 1, 6), x1 = min(x0 + 1, 6);
        float wy = fy - y0, wx = fx - x0;
        float val = (1.f - wy) * ((1.f - wx) * bb[y0 * 7 + x0] + wx * bb[y0 * 7 + x1])
                  + wy * ((1.f - wx) * bb[y1 * 7 + x0] + wx * bb[y1 * 7 + x1]);
        pbias[(size_t)bid * 4096 + pos] = val + ay[y] + ax[x];
    }
}

// ---------------------------------------------------------------------------
// K3b: abiasT[h][a][pos] (bilerp + ha + wa), TRANSPOSED layout so stage2 reads
// are pos-coalesced.  grid 392, block 256.
// ---------------------------------------------------------------------------
__global__ __launch_bounds__(256) void make_abias(
    const float* __restrict__ na, const float* __restrict__ hab,
    const float* __restrict__ wab, float* __restrict__ abiasT)
{
    int bid = blockIdx.x;               // h*49 + a
    int h = bid / 49, a = bid % 49;
    __shared__ float bb[49], hy[64], wx_[64];
    int tid = threadIdx.x;
    if (tid < 49) bb[tid] = na[(size_t)bid * 49 + tid];
    if (tid < 64) {
        hy[tid]  = hab[((size_t)(h * 64) + tid) * 49 + a];
        wx_[tid] = wab[((size_t)(h * 64) + tid) * 49 + a];
    }
    __syncthreads();
    for (int it = 0; it < 16; ++it) {
        int pos = it * 256 + tid;
        int y = pos >> 6, x = pos & 63;
        float fy = (y + 0.5f) * (7.f / 64.f) - 0.5f; fy = fminf(fmaxf(fy, 0.f), 6.f);
        float fx = (x + 0.5f) * (7.f / 64.f) - 0.5f; fx = fminf(fmaxf(fx, 0.f), 6.f);
        int y0 = (int)fy, x0 = (int)fx;
        int y1 = min(y0 + 1, 6), x1 = min(x0 + 1, 6);
        float wy = fy - y0, wxv = fx - x0;
        float val = (1.f - wy) * ((1.f - wxv) * bb[y0 * 7 + x0] + wxv * bb[y0 * 7 + x1])
                  + wy * ((1.f - wxv) * bb[y1 * 7 + x0] + wxv * bb[y1 * 7 + x1]);
        abiasT[(size_t)bid * 4096 + pos] = val + hy[y] + wx_[x];
    }
}

// ---------------------------------------------------------------------------
// K4: stage-1 attention via MFMA (linear softmax, split over n).
// grid 1024 (=16*8*8 splits of 512), block 256 (4 waves).
// Per 128-n subtile: S = agent.K^T (mfma) -> exp -> P in LDS (bf16, A-frag
// layout) ; V transposed into vT LDS ; O += P.V (mfma).  Z via per-lane
// accumulation + shfl_xor reduce.  Partials to part_O/part_sum.
// ---------------------------------------------------------------------------
__global__ __launch_bounds__(256) void stage1(
    const float* __restrict__ agent, const bf16* __restrict__ k,
    const bf16* __restrict__ v, const float* __restrict__ pbias,
    float* __restrict__ part_O, float* __restrict__ part_sum)
{
    const int bid = blockIdx.x;
    const int split = bid & 7, h = (bid >> 3) & 7, b = bid >> 6;
    const int tid = threadIdx.x;
    const int w = tid >> 6, lane = tid & 63;
    const int ln = lane & 15, quad = lane >> 4;

    __shared__ __align__(16) short agLds[64 * 32];    // [a][d] bf16
    __shared__ __align__(16) short pLds[64 * 140];    // [a][n_loc] bf16, pad->140
    __shared__ __align__(16) short vtLds[32 * 140];   // [d][n_loc] bf16

    // stage agents once: rows >= 49 zeroed
    for (int i = tid; i < 64 * 32; i += 256) {
        int a = i >> 5, d = i & 31;
        float val = (a < 49) ? agent[((size_t)(b * 49) + a) * 256 + h * 32 + d] : 0.f;
        agLds[i] = (short)f2bf(val);
    }
    __syncthreads();

    const short8 agFrag = *reinterpret_cast<const short8*>(&agLds[(w * 16 + ln) * 32 + quad * 8]);
    const int a_row = w * 16 + quad * 4;    // + r gives agent index

    f32x4 oAcc[2] = {};
    float sacc[4] = {0.f, 0.f, 0.f, 0.f};
    const f32x4 zero4 = {0.f, 0.f, 0.f, 0.f};

    for (int sub = 0; sub < 4; ++sub) {
        const int nbase = split * 512 + sub * 128;
        __syncthreads();     // pLds/vtLds free from previous sub's PV
        // ---- vT staging: thread t -> n_loc = t&127, d-half = (t>>7)*16
        {
            const int n_loc = tid & 127, dh = (tid >> 7) * 16;
            const short* vr = (const short*)v + ((size_t)(b * 4096) + nbase + n_loc) * 256 + h * 32 + dh;
            uint4 u0 = *reinterpret_cast<const uint4*>(vr);
            uint4 u1 = *reinterpret_cast<const uint4*>(vr + 8);
            unsigned int uu[8] = {u0.x, u0.y, u0.z, u0.w, u1.x, u1.y, u1.z, u1.w};
            #pragma unroll
            for (int j = 0; j < 8; ++j) {
                vtLds[(dh + 2 * j) * 140 + n_loc]     = (short)(uu[j] & 0xffffu);
                vtLds[(dh + 2 * j + 1) * 140 + n_loc] = (short)(uu[j] >> 16);
            }
        }
        // ---- score: wave w computes S rows [w*16,w*16+16) x 128 cols
        short8 kf[8];
        #pragma unroll
        for (int t = 0; t < 8; ++t) {
            int n = nbase + t * 16 + ln;
            kf[t] = *reinterpret_cast<const short8*>(
                (const short*)k + ((size_t)(b * 4096) + n) * 256 + h * 32 + quad * 8);
        }
        #pragma unroll
        for (int t = 0; t < 8; ++t) {
            f32x4 s = __builtin_amdgcn_mfma_f32_16x16x32_bf16(agFrag, kf[t], zero4, 0, 0, 0);
            int n = nbase + t * 16 + ln;
            #pragma unroll
            for (int r = 0; r < 4; ++r) {
                int a = a_row + r;
                float e = 0.f;
                if (a < 49) {
                    float sv = s[r] * SCALE + pbias[((size_t)(h * 49) + a) * 4096 + n];
                    e = __expf(sv);
                }
                sacc[r] += e;
                pLds[(a_row + r) * 140 + t * 16 + ln] = (short)f2bf(e);
            }
        }
        __syncthreads();     // pLds + vtLds ready
        // ---- PV: O[m=a][d] += P . V, K = 128 (4 mfma k-steps)
        #pragma unroll
        for (int ks = 0; ks < 4; ++ks) {
            short8 pf = *reinterpret_cast<const short8*>(&pLds[(w * 16 + ln) * 140 + ks * 32 + quad * 8]);
            #pragma unroll
            for (int dt = 0; dt < 2; ++dt) {
                short8 vf = *reinterpret_cast<const short8*>(&vtLds[(dt * 16 + ln) * 140 + ks * 32 + quad * 8]);
                oAcc[dt] = __builtin_amdgcn_mfma_f32_16x16x32_bf16(pf, vf, oAcc[dt], 0, 0, 0);
            }
        }
    }

    // ---- write partials
    const size_t obase = ((size_t)((b * 8 + h) * 8 + split)) * 1568;
    #pragma unroll
    for (int dt = 0; dt < 2; ++dt)
        #pragma unroll
        for (int r = 0; r < 4; ++r) {
            int a = a_row + r;
            if (a < 49)
                part_O[obase + a * 32 + dt * 16 + ln] = oAcc[dt][r];
        }
    #pragma unroll
    for (int r = 0; r < 4; ++r) {
        float sv = sacc[r];
        #pragma unroll
        for (int m = 1; m < 16; m <<= 1) sv += __shfl_xor(sv, m, 64);
        if (ln == 0) {
            int a = a_row + r;
            if (a < 49)
                part_sum[((b * 8 + h) * 8 + split) * 49 + a] = sv;
        }
    }
}

// K4b: combine split partials.  grid 128 (b*8+h), block 256.
__global__ __launch_bounds__(256) void stage1_fin(
    const float* __restrict__ part_O, const float* __restrict__ part_sum,
    float* __restrict__ agent_v)
{
    int bh = blockIdx.x;
    __shared__ float inv[49];
    int tid = threadIdx.x;
    if (tid < 49) {
        float s = 0.f;
        #pragma unroll
        for (int sp = 0; sp < 8; ++sp) s += part_sum[(bh * 8 + sp) * 49 + tid];
        inv[tid] = 1.f / s;
    }
    __syncthreads();
    for (int idx = tid; idx < 1568; idx += 256) {
        float o = 0.f;
        #pragma unroll
        for (int sp = 0; sp < 8; ++sp) o += part_O[((size_t)(bh * 8) + sp) * 1568 + idx];
        agent_v[(size_t)bh * 1568 + idx] = o * inv[idx >> 5];
    }
}

// ---------------------------------------------------------------------------
// K5: stage-2 attention, zero-LDS.  Linear softmax streamed over a;
// ag/av/wd/bd via wave-uniform scalar loads; abiasT pos-coalesced.
// One thread per (b,h,pos).  grid (128, 16), block 256.
// ---------------------------------------------------------------------------
__global__ __launch_bounds__(256) void stage2(
    const bf16* __restrict__ q, const bf16* __restrict__ v,
    const float* __restrict__ agent, const float* __restrict__ agent_v,
    const float* __restrict__ abiasT, const float* __restrict__ wdwc,
    const float* __restrict__ bdwc, bf16* __restrict__ mid)
{
    const int bh = blockIdx.x;
    const int b = bh >> 3, h = bh & 7;
    const int pos = blockIdx.y * 256 + threadIdx.x;

    const float* agb = agent + ((size_t)(b * 49)) * 256 + h * 32;
    const float* avb = agent_v + (size_t)bh * 1568;
    const float* abb = abiasT + (size_t)(h * 49) * 4096 + pos;
    const float* wdb = wdwc + (size_t)(h * 32) * 9;
    const float* bdb = bdwc + h * 32;

    float qv[32];
    {
        const bf16* qr = q + ((size_t)(b * 4096) + pos) * 256 + h * 32;
        #pragma unroll
        for (int u = 0; u < 4; ++u) {
            float f[8]; load8bf(qr + u * 8, f);
            #pragma unroll
            for (int d = 0; d < 8; ++d) qv[u * 8 + d] = f[d] * SCALE;
        }
    }

    float sum = 0.f;
    float acc[32];
    #pragma unroll
    for (int d = 0; d < 32; ++d) acc[d] = 0.f;

    for (int a = 0; a < 49; ++a) {
        const float* ag = agb + (size_t)a * 256;   // wave-uniform
        const float* av = avb + a * 32;            // wave-uniform
        float t = abb[(size_t)a * 4096];           // coalesced vector load
        #pragma unroll
        for (int d = 0; d < 32; ++d) t = fmaf(qv[d], ag[d], t);
        float e = __expf(t);
        sum += e;
        #pragma unroll
        for (int d = 0; d < 32; ++d) acc[d] = fmaf(e, av[d], acc[d]);
    }
    float inv = 1.f / sum;
    #pragma unroll
    for (int d = 0; d < 32; ++d) acc[d] *= inv;

    int y = pos >> 6, x = pos & 63;
    #pragma unroll
    for (int dy = -1; dy <= 1; ++dy) {
        int yy = y + dy; if (yy < 0 || yy > 63) continue;
        #pragma unroll
        for (int dx = -1; dx <= 1; ++dx) {
            int xx = x + dx; if (xx < 0 || xx > 63) continue;
            const bf16* vr = v + ((size_t)(b * 4096) + yy * 64 + xx) * 256 + h * 32;
            int widx = (dy + 1) * 3 + (dx + 1);
            #pragma unroll
            for (int u = 0; u < 4; ++u) {
                float f[8]; load8bf(vr + u * 8, f);
                #pragma unroll
                for (int d = 0; d < 8; ++d)
                    acc[u * 8 + d] = fmaf(wdb[(u * 8 + d) * 9 + widx], f[d], acc[u * 8 + d]);
            }
        }
    }
    #pragma unroll
    for (int d = 0; d < 32; ++d) acc[d] += bdb[d];

    bf16* dst = mid + ((size_t)(b * 4096) + pos) * 256 + h * 32;
    #pragma unroll
    for (int u = 0; u < 4; ++u) {
        ushort4 w;
        w.x = f2bf(acc[u * 8 + 0]);
        w.y = f2bf(acc[u * 8 + 1]);
        w.z = f2bf(acc[u * 8 + 2]);
        w.w = f2bf(acc[u * 8 + 3]);
        ushort4 w2;
        w2.x = f2bf(acc[u * 8 + 4]);
        w2.y = f2bf(acc[u * 8 + 5]);
        w2.z = f2bf(acc[u * 8 + 6]);
        w2.w = f2bf(acc[u * 8 + 7]);
        *reinterpret_cast<ushort4*>(dst + u * 8)     = w;
        *reinterpret_cast<ushort4*>(dst + u * 8 + 4) = w2;
    }
}

// ---------------------------------------------------------------------------
// K7: proj MFMA GEMM.  D[m=ch][n=pos] = Wp (256x256) . mid[b]^T (256x4096).
// grid (2, 512), block 256.
// ---------------------------------------------------------------------------
__global__ __launch_bounds__(256) void proj_mfma(
    const bf16* __restrict__ mid, const bf16* __restrict__ Wp,
    const float* __restrict__ bp, float* __restrict__ out)
{
    __shared__ __align__(16) short As[128 * 32];
    __shared__ __align__(16) short Bs[128 * 32];
    const int m0 = blockIdx.x * 128;           // ch tile
    const int b  = blockIdx.y >> 5;
    const int n0 = (blockIdx.y & 31) * 128;    // pos tile
    const int tid = threadIdx.x;
    const int w = tid >> 6, lane = tid & 63;
    const int wm = w & 1, wn = w >> 1;
    const int quad = lane >> 4, ln = lane & 15;

    const short* Ag = (const short*)Wp + (size_t)m0 * 256;
    const short* Bg = (const short*)mid + ((size_t)(b * 4096 + n0)) * 256;
    const int ldrow = lane >> 2;
    const int ldcol = (lane & 3) * 8;

    f32x4 acc[4][4] = {};

    for (int k0 = 0; k0 < 256; k0 += 32) {
        __syncthreads();
        #pragma unroll
        for (int p = 0; p < 2; ++p) {
            int row = w * 32 + p * 16;
            gload16(Ag + (size_t)(row + ldrow) * 256 + k0 + ldcol, As + row * 32);
            gload16(Bg + (size_t)(row + ldrow) * 256 + k0 + ldcol, Bs + row * 32);
        }
        __syncthreads();
        short8 af[4], bfr[4];
        #pragma unroll
        for (int mi = 0; mi < 4; ++mi)
            af[mi] = *reinterpret_cast<const short8*>(&As[(wm * 64 + mi * 16 + ln) * 32 + quad * 8]);
        #pragma unroll
        for (int ni = 0; ni < 4; ++ni)
            bfr[ni] = *reinterpret_cast<const short8*>(&Bs[(wn * 64 + ni * 16 + ln) * 32 + quad * 8]);
        #pragma unroll
        for (int mi = 0; mi < 4; ++mi)
            #pragma unroll
            for (int ni = 0; ni < 4; ++ni)
                acc[mi][ni] = __builtin_amdgcn_mfma_f32_16x16x32_bf16(
                    af[mi], bfr[ni], acc[mi][ni], 0, 0, 0);
    }

    #pragma unroll
    for (int mi = 0; mi < 4; ++mi)
        #pragma unroll
        for (int r = 0; r < 4; ++r) {
            int ch = m0 + wm * 64 + mi * 16 + quad * 4 + r;
            float bias = bp[ch];
            float* o = out + ((size_t)(b * 256 + ch)) * 4096 + n0 + wn * 64 + ln;
            #pragma unroll
            for (int ni = 0; ni < 4; ++ni)
                o[ni * 16] = acc[mi][ni][r] + bias;
        }
}

extern "C" void kernel_launch(void* const* d_in, const int* in_sizes, int n_in,
                              void* d_out, int out_size, void* d_ws, size_t ws_size,
                              hipStream_t stream)
{
    const float* x       = (const float*)d_in[0];
    const float* Wq      = (const float*)d_in[1];
    const float* Wkv     = (const float*)d_in[2];
    const float* Wproj   = (const float*)d_in[3];
    const float* bproj   = (const float*)d_in[4];
    const float* Wdwc    = (const float*)d_in[5];
    const float* bdwc    = (const float*)d_in[6];
    const float* an_bias = (const float*)d_in[7];
    const float* na_bias = (const float*)d_in[8];
    const float* ah_bias = (const float*)d_in[9];
    const float* aw_bias = (const float*)d_in[10];
    const float* ha_bias = (const float*)d_in[11];
    const float* wa_bias = (const float*)d_in[12];
    // H=64, W=64 hard-coded (d_in[13], d_in[14])

    char* ws = (char*)d_ws;
    bf16*  q      = (bf16*)(ws + 0);
    bf16*  k      = (bf16*)(ws + 33554432);
    bf16*  v      = (bf16*)(ws + 67108864);
    // the 33.5 MB region at 100663296 is triple-used over time:
    //   1) xT (qkv input), 2) stage1 partials, 3) mid (stage2 out / proj in)
    bf16*  xT     = (bf16*)(ws + 100663296);
    float* part_O   = (float*)(ws + 100663296);
    float* part_sum = (float*)(ws + 100663296 + 6422528);
    bf16*  mid    = (bf16*)(ws + 100663296);
    float* agent  = (float*)(ws + 134217728);
    float* agentv = (float*)(ws + 135020544);
    float* pbias  = (float*)(ws + 135823360);
    float* abiasT = (float*)(ws + 142245888);
    bf16*  Wqkv_bf = (bf16*)(ws + 148668416);
    bf16*  Wp_bf   = (bf16*)(ws + 149061632);
    float* out    = (float*)d_out;

    convert_w <<<dim3(1024),     256, 0, stream>>>(Wq, Wkv, Wproj, Wqkv_bf, Wp_bf);
    x_to_bf16T<<<dim3(64, 4, 16),256, 0, stream>>>(x, xT);
    qkv_mfma  <<<dim3(512, 6),   256, 0, stream>>>(xT, Wqkv_bf, q, k, v);
    pool_agent<<<dim3(784),      256, 0, stream>>>(q, agent);
    make_pbias<<<dim3(392),      256, 0, stream>>>(an_bias, ah_bias, aw_bias, pbias);
    make_abias<<<dim3(392),      256, 0, stream>>>(na_bias, ha_bias, wa_bias, abiasT);
    stage1    <<<dim3(1024),     256, 0, stream>>>(agent, k, v, pbias, part_O, part_sum);
    stage1_fin<<<dim3(128),      256, 0, stream>>>(part_O, part_sum, agentv);
    stage2    <<<dim3(128, 16),  256, 0, stream>>>(q, v, agent, agentv, abiasT, Wdwc, bdwc, mid);
    proj_mfma <<<dim3(2, 512),   256, 0, stream>>>(mid, Wp_bf, bproj, out);
}